// Round 1
// baseline (2374.235 us; speedup 1.0000x reference)
//
#include <hip/hip_runtime.h>

#define NG 50000
#define NC 100000
#define DIN 128
#define D 64
#define EGG 800000
#define ECG 1600000
#define ECC 1600000
#define LN_EPS 1e-5f

__device__ __forceinline__ float wave_sum64(float v) {
#pragma unroll
  for (int off = 32; off > 0; off >>= 1) v += __shfl_xor(v, off);
  return v;
}

// y = relu(LN(x @ W + b)) ; x:[n,128] W:[128,64] -> y:[n,64]. One wave per row.
__global__ __launch_bounds__(256) void fc_in_kernel(
    const float* __restrict__ x, const float* __restrict__ W,
    const float* __restrict__ b, const float* __restrict__ s,
    const float* __restrict__ beta, float* __restrict__ y, int n) {
  int wid = (int)(((size_t)blockIdx.x * blockDim.x + threadIdx.x) >> 6);
  int lane = threadIdx.x & 63;
  if (wid >= n) return;
  const float* xr = x + (size_t)wid * DIN;
  float v0 = xr[lane];
  float v1 = xr[64 + lane];
  float acc = b[lane];
#pragma unroll
  for (int k = 0; k < 64; ++k)
    acc = fmaf(__shfl(v0, k), W[k * 64 + lane], acc);
#pragma unroll
  for (int k = 0; k < 64; ++k)
    acc = fmaf(__shfl(v1, k), W[(k + 64) * 64 + lane], acc);
  float m = wave_sum64(acc) * (1.0f / 64.0f);
  float d = acc - m;
  float var = wave_sum64(d * d) * (1.0f / 64.0f);
  float o = d * rsqrtf(var + LN_EPS) * s[lane] + beta[lane];
  y[(size_t)wid * D + lane] = fmaxf(o, 0.0f);
}

// xt = xg @ W ; A = dinv^2 * xt + b  (GCN transform + self-loop init). Wave/row.
__global__ __launch_bounds__(256) void gcn_xt_kernel(
    const float* __restrict__ xg, const float* __restrict__ W,
    const float* __restrict__ b, const float* __restrict__ dinv,
    float* __restrict__ xt, float* __restrict__ A, int n) {
  int wid = (int)(((size_t)blockIdx.x * blockDim.x + threadIdx.x) >> 6);
  int lane = threadIdx.x & 63;
  if (wid >= n) return;
  size_t idx = (size_t)wid * D + lane;
  float v = xg[idx];
  float acc = 0.0f;
#pragma unroll
  for (int k = 0; k < 64; ++k)
    acc = fmaf(__shfl(v, k), W[k * 64 + lane], acc);
  xt[idx] = acc;
  float di = dinv[wid];
  A[idx] = di * di * acc + b[lane];
}

// deg[col] += ew[e]   (one thread per edge)
__global__ __launch_bounds__(256) void deg_kernel(
    const int* __restrict__ ei, const float* __restrict__ ew,
    float* __restrict__ deg) {
  int e = blockIdx.x * 256 + threadIdx.x;
  if (e >= EGG) return;
  atomicAdd(&deg[ei[EGG + e]], ew[e]);
}

// deg -> rsqrt(deg + 1)   (self-loop weight 1; deg >= 1 so no zero guard needed)
__global__ __launch_bounds__(256) void dinv_kernel(float* __restrict__ deg, int n) {
  int i = blockIdx.x * 256 + threadIdx.x;
  if (i < n) deg[i] = rsqrtf(deg[i] + 1.0f);
}

// A[col] += dinv[row]*ew*dinv[col] * xt[row]   (one wave per edge, lane = dim)
__global__ __launch_bounds__(256) void scatter_gg_kernel(
    const int* __restrict__ ei, const float* __restrict__ ew,
    const float* __restrict__ dinv, const float* __restrict__ xt,
    float* __restrict__ A) {
  int e = (int)(((size_t)blockIdx.x * blockDim.x + threadIdx.x) >> 6);
  int lane = threadIdx.x & 63;
  if (e >= EGG) return;
  int r = ei[e];
  int c = ei[EGG + e];
  float norm = dinv[r] * ew[e] * dinv[c];
  atomicAdd(&A[(size_t)c * D + lane], norm * xt[(size_t)r * D + lane]);
}

// agg[col] += xs[row]   (GIN aggregation; one wave per edge)
__global__ __launch_bounds__(256) void scatter_gin_kernel(
    const int* __restrict__ ei, const float* __restrict__ xs,
    float* __restrict__ agg, int E) {
  int e = (int)(((size_t)blockIdx.x * blockDim.x + threadIdx.x) >> 6);
  int lane = threadIdx.x & 63;
  if (e >= E) return;
  int r = ei[e];
  int c = ei[E + e];
  atomicAdd(&agg[(size_t)c * D + lane], xs[(size_t)r * D + lane]);
}

// xg = relu(LN( A + relu(((1+eps)*xg + B) @ W + b) ))   in-place per row.
__global__ __launch_bounds__(256) void glom_update_kernel(
    const float* __restrict__ A, const float* __restrict__ B,
    float* __restrict__ xg, const float* __restrict__ W,
    const float* __restrict__ b, const float* __restrict__ eps,
    const float* __restrict__ ls, const float* __restrict__ lb, int n) {
  int wid = (int)(((size_t)blockIdx.x * blockDim.x + threadIdx.x) >> 6);
  int lane = threadIdx.x & 63;
  if (wid >= n) return;
  size_t idx = (size_t)wid * D + lane;
  float h = (1.0f + eps[0]) * xg[idx] + B[idx];
  float acc = b[lane];
#pragma unroll
  for (int k = 0; k < 64; ++k)
    acc = fmaf(__shfl(h, k), W[k * 64 + lane], acc);
  float g = A[idx] + fmaxf(acc, 0.0f);
  float m = wave_sum64(g) * (1.0f / 64.0f);
  float d = g - m;
  float var = wave_sum64(d * d) * (1.0f / 64.0f);
  float o = d * rsqrtf(var + LN_EPS) * ls[lane] + lb[lane];
  xg[idx] = fmaxf(o, 0.0f);
}

// xc = relu(LN( relu(((1+eps)*xc + C) @ W + b) ))   in-place per row.
__global__ __launch_bounds__(256) void cell_update_kernel(
    const float* __restrict__ C, float* __restrict__ xc,
    const float* __restrict__ W, const float* __restrict__ b,
    const float* __restrict__ eps, const float* __restrict__ ls,
    const float* __restrict__ lb, int n) {
  int wid = (int)(((size_t)blockIdx.x * blockDim.x + threadIdx.x) >> 6);
  int lane = threadIdx.x & 63;
  if (wid >= n) return;
  size_t idx = (size_t)wid * D + lane;
  float h = (1.0f + eps[0]) * xc[idx] + C[idx];
  float acc = b[lane];
#pragma unroll
  for (int k = 0; k < 64; ++k)
    acc = fmaf(__shfl(h, k), W[k * 64 + lane], acc);
  float g = fmaxf(acc, 0.0f);
  float m = wave_sum64(g) * (1.0f / 64.0f);
  float d = g - m;
  float var = wave_sum64(d * d) * (1.0f / 64.0f);
  float o = d * rsqrtf(var + LN_EPS) * ls[lane] + lb[lane];
  xc[idx] = fmaxf(o, 0.0f);
}

// out = softmax(xg @ W_out + b_out)  ; one thread per row (3 outputs).
__global__ __launch_bounds__(256) void out_kernel(
    const float* __restrict__ xg, const float* __restrict__ W,
    const float* __restrict__ b, float* __restrict__ out, int n) {
  int r = blockIdx.x * 256 + threadIdx.x;
  if (r >= n) return;
  float a0 = b[0], a1 = b[1], a2 = b[2];
  const float* xr = xg + (size_t)r * D;
#pragma unroll
  for (int k = 0; k < 64; ++k) {
    float v = xr[k];
    a0 = fmaf(v, W[k * 3 + 0], a0);
    a1 = fmaf(v, W[k * 3 + 1], a1);
    a2 = fmaf(v, W[k * 3 + 2], a2);
  }
  float m = fmaxf(a0, fmaxf(a1, a2));
  float e0 = expf(a0 - m), e1 = expf(a1 - m), e2 = expf(a2 - m);
  float inv = 1.0f / (e0 + e1 + e2);
  out[(size_t)r * 3 + 0] = e0 * inv;
  out[(size_t)r * 3 + 1] = e1 * inv;
  out[(size_t)r * 3 + 2] = e2 * inv;
}

extern "C" void kernel_launch(void* const* d_in, const int* in_sizes, int n_in,
                              void* d_out, int out_size, void* d_ws, size_t ws_size,
                              hipStream_t stream) {
  const float* x_glom = (const float*)d_in[0];
  const float* x_cell = (const float*)d_in[1];
  const int*   ei_gg  = (const int*)d_in[2];
  const float* ew_gg  = (const float*)d_in[3];
  const int*   ei_cg  = (const int*)d_in[4];
  const int*   ei_cc  = (const int*)d_in[5];
  const float* W_in_g = (const float*)d_in[6];
  const float* b_in_g = (const float*)d_in[7];
  const float* lnig_s = (const float*)d_in[8];
  const float* lnig_b = (const float*)d_in[9];
  const float* W_in_c = (const float*)d_in[10];
  const float* b_in_c = (const float*)d_in[11];
  const float* lnic_s = (const float*)d_in[12];
  const float* lnic_b = (const float*)d_in[13];
  const float* W_outp = (const float*)d_in[34];
  const float* b_outp = (const float*)d_in[35];

  // workspace layout (floats). B aliases xt: xt is dead once scatter_gg is done,
  // and B is first written (memset) after that point.
  float* ws   = (float*)d_ws;
  float* xg   = ws;                          // NG*64
  float* xc   = xg + (size_t)NG * D;         // NC*64
  float* xt   = xc + (size_t)NC * D;         // NG*64 (aliased as B)
  float* A    = xt + (size_t)NG * D;         // NG*64
  float* Cagg = A  + (size_t)NG * D;         // NC*64
  float* dinv = Cagg + (size_t)NC * D;       // NG
  float* B = xt;

  dim3 blk(256);
  auto wgrid = [](long long waves) { return dim3((unsigned)((waves + 3) / 4)); };

  // input FCs
  fc_in_kernel<<<wgrid(NG), blk, 0, stream>>>(x_glom, W_in_g, b_in_g, lnig_s, lnig_b, xg, NG);
  fc_in_kernel<<<wgrid(NC), blk, 0, stream>>>(x_cell, W_in_c, b_in_c, lnic_s, lnic_b, xc, NC);

  // GCN degree normalization (same edges both layers -> compute once)
  hipMemsetAsync(dinv, 0, NG * sizeof(float), stream);
  deg_kernel<<<dim3((EGG + 255) / 256), blk, 0, stream>>>(ei_gg, ew_gg, dinv);
  dinv_kernel<<<dim3((NG + 255) / 256), blk, 0, stream>>>(dinv, NG);

  for (int l = 0; l < 2; ++l) {
    const float* const* p = (const float* const*)(d_in + 14 + 10 * l);
    const float* W_gcn = p[0]; const float* b_gcn = p[1];
    const float* eps_cg = p[2]; const float* W_cg = p[3]; const float* b_cg = p[4];
    const float* eps_cc = p[5]; const float* W_cc = p[6]; const float* b_cc = p[7];
    const float* ln_s = p[8]; const float* ln_b = p[9];

    gcn_xt_kernel<<<wgrid(NG), blk, 0, stream>>>(xg, W_gcn, b_gcn, dinv, xt, A, NG);
    scatter_gg_kernel<<<dim3(EGG / 4), blk, 0, stream>>>(ei_gg, ew_gg, dinv, xt, A);

    hipMemsetAsync(B, 0, (size_t)NG * D * sizeof(float), stream);
    scatter_gin_kernel<<<dim3(ECG / 4), blk, 0, stream>>>(ei_cg, xc, B, ECG);

    hipMemsetAsync(Cagg, 0, (size_t)NC * D * sizeof(float), stream);
    scatter_gin_kernel<<<dim3(ECC / 4), blk, 0, stream>>>(ei_cc, xc, Cagg, ECC);

    glom_update_kernel<<<wgrid(NG), blk, 0, stream>>>(A, B, xg, W_cg, b_cg, eps_cg, ln_s, ln_b, NG);
    cell_update_kernel<<<wgrid(NC), blk, 0, stream>>>(Cagg, xc, W_cc, b_cc, eps_cc, ln_s, ln_b, NC);
  }

  out_kernel<<<dim3((NG + 255) / 256), blk, 0, stream>>>(xg, W_outp, b_outp, (float*)d_out, NG);
}

// Round 2
// 1863.379 us; speedup vs baseline: 1.2742x; 1.2742x over previous
//
#include <hip/hip_runtime.h>

#define NG 50000
#define NC 100000
#define DIN 128
#define D 64
#define EGG 800000
#define ECG 1600000
#define ECC 1600000
#define LN_EPS 1e-5f

__device__ __forceinline__ float wave_sum64(float v) {
#pragma unroll
  for (int off = 32; off > 0; off >>= 1) v += __shfl_xor(v, off);
  return v;
}

// ---------------- dense input FC: y = relu(LN(x @ W + b)), wave per row ----
__global__ __launch_bounds__(256) void fc_in_kernel(
    const float* __restrict__ x, const float* __restrict__ W,
    const float* __restrict__ b, const float* __restrict__ s,
    const float* __restrict__ beta, float* __restrict__ y, int n) {
  int wid = (int)(((size_t)blockIdx.x * blockDim.x + threadIdx.x) >> 6);
  int lane = threadIdx.x & 63;
  if (wid >= n) return;
  const float* xr = x + (size_t)wid * DIN;
  float v0 = xr[lane];
  float v1 = xr[64 + lane];
  float acc = b[lane];
#pragma unroll
  for (int k = 0; k < 64; ++k)
    acc = fmaf(__shfl(v0, k), W[k * 64 + lane], acc);
#pragma unroll
  for (int k = 0; k < 64; ++k)
    acc = fmaf(__shfl(v1, k), W[(k + 64) * 64 + lane], acc);
  float m = wave_sum64(acc) * (1.0f / 64.0f);
  float d = acc - m;
  float var = wave_sum64(d * d) * (1.0f / 64.0f);
  float o = d * rsqrtf(var + LN_EPS) * s[lane] + beta[lane];
  y[(size_t)wid * D + lane] = fmaxf(o, 0.0f);
}

// ---------------- CSR build ------------------------------------------------
// cnt[dst]++ per edge (dst = ei[E+e])
__global__ __launch_bounds__(256) void count_kernel(
    const int* __restrict__ ei, int* __restrict__ cnt, int E) {
  int e = blockIdx.x * 256 + threadIdx.x;
  if (e >= E) return;
  atomicAdd(&cnt[ei[E + e]], 1);
}

// weighted degree for GCN: deg[col] += ew[e]
__global__ __launch_bounds__(256) void deg_kernel(
    const int* __restrict__ ei, const float* __restrict__ ew,
    float* __restrict__ deg) {
  int e = blockIdx.x * 256 + threadIdx.x;
  if (e >= EGG) return;
  atomicAdd(&deg[ei[EGG + e]], ew[e]);
}

__global__ __launch_bounds__(256) void dinv_kernel(float* __restrict__ deg, int n) {
  int i = blockIdx.x * 256 + threadIdx.x;
  if (i < n) deg[i] = rsqrtf(deg[i] + 1.0f);
}

// three exclusive prefix sums (one block each): rp[0..n] from cnt[0..n-1]
__global__ __launch_bounds__(1024) void scan3_kernel(
    const int* __restrict__ c0, int* __restrict__ r0, int n0,
    const int* __restrict__ c1, int* __restrict__ r1, int n1,
    const int* __restrict__ c2, int* __restrict__ r2, int n2) {
  const int* cnt; int* rp; int n;
  if (blockIdx.x == 0) { cnt = c0; rp = r0; n = n0; }
  else if (blockIdx.x == 1) { cnt = c1; rp = r1; n = n1; }
  else { cnt = c2; rp = r2; n = n2; }
  __shared__ int sh[1024];
  __shared__ int carry_sh;
  int tid = threadIdx.x;
  if (tid == 0) carry_sh = 0;
  __syncthreads();
  for (int base = 0; base < n; base += 1024) {
    int i = base + tid;
    int v = (i < n) ? cnt[i] : 0;
    sh[tid] = v;
    __syncthreads();
#pragma unroll
    for (int off = 1; off < 1024; off <<= 1) {
      int t = (tid >= off) ? sh[tid - off] : 0;
      __syncthreads();
      sh[tid] += t;
      __syncthreads();
    }
    int carry = carry_sh;
    if (i < n) rp[i] = carry + sh[tid] - v;
    __syncthreads();
    if (tid == 1023) carry_sh = carry + sh[1023];
    __syncthreads();
  }
  if (tid == 0) rp[n] = carry_sh;
}

// fill: pos = cur[dst]++; src[pos] = src_node  (GIN relations)
__global__ __launch_bounds__(256) void fill_gin_kernel(
    const int* __restrict__ ei, int* __restrict__ cur,
    int* __restrict__ src, int E) {
  int e = blockIdx.x * 256 + threadIdx.x;
  if (e >= E) return;
  int c = ei[E + e];
  int pos = atomicAdd(&cur[c], 1);
  src[pos] = ei[e];
}

// fill for GCN: also precompute norm = dinv[r]*ew*dinv[c]
__global__ __launch_bounds__(256) void fill_gg_kernel(
    const int* __restrict__ ei, const float* __restrict__ ew,
    const float* __restrict__ dinv, int* __restrict__ cur,
    int* __restrict__ src, float* __restrict__ nrm) {
  int e = blockIdx.x * 256 + threadIdx.x;
  if (e >= EGG) return;
  int r = ei[e];
  int c = ei[EGG + e];
  int pos = atomicAdd(&cur[c], 1);
  src[pos] = r;
  nrm[pos] = dinv[r] * ew[e] * dinv[c];
}

// ---------------- fused glom layer -----------------------------------------
// per row i (one wave):
//   accG = dinv[i]^2*xg[i] + sum_e norm_e * xg[src_e]      (GCN gather, pre-W)
//   accC = sum_e xc[src_e]                                  (GIN-CG gather)
//   g = (accG @ W_gcn + b_gcn) + relu(((1+eps)xg[i]+accC) @ W_cg + b_cg)
//   xg_new[i] = relu(LN(g))
__global__ __launch_bounds__(256) void glom_layer_kernel(
    const int* __restrict__ rp_gg, const int* __restrict__ src_gg,
    const float* __restrict__ nrm_gg,
    const int* __restrict__ rp_cg, const int* __restrict__ src_cg,
    const float* __restrict__ xg_old, const float* __restrict__ xc_old,
    const float* __restrict__ dinv,
    const float* __restrict__ W_gcn, const float* __restrict__ b_gcn,
    const float* __restrict__ eps_cg, const float* __restrict__ W_cg,
    const float* __restrict__ b_cg,
    const float* __restrict__ ls, const float* __restrict__ lb,
    float* __restrict__ xg_new, int n) {
  int i = (int)(((size_t)blockIdx.x * blockDim.x + threadIdx.x) >> 6);
  int lane = threadIdx.x & 63;
  if (i >= n) return;
  float self = xg_old[(size_t)i * D + lane];
  float di = dinv[i];
  float accG = di * di * self;
  int e0 = rp_gg[i], e1 = rp_gg[i + 1];
  for (int e = e0; e < e1; ++e)
    accG = fmaf(nrm_gg[e], xg_old[(size_t)src_gg[e] * D + lane], accG);
  float accC = 0.0f;
  int f0 = rp_cg[i], f1 = rp_cg[i + 1];
  for (int e = f0; e < f1; ++e)
    accC += xc_old[(size_t)src_cg[e] * D + lane];
  float gcn = b_gcn[lane];
#pragma unroll
  for (int k = 0; k < 64; ++k)
    gcn = fmaf(__shfl(accG, k), W_gcn[k * 64 + lane], gcn);
  float h = (1.0f + eps_cg[0]) * self + accC;
  float gin = b_cg[lane];
#pragma unroll
  for (int k = 0; k < 64; ++k)
    gin = fmaf(__shfl(h, k), W_cg[k * 64 + lane], gin);
  float g = gcn + fmaxf(gin, 0.0f);
  float m = wave_sum64(g) * (1.0f / 64.0f);
  float d = g - m;
  float var = wave_sum64(d * d) * (1.0f / 64.0f);
  float o = d * rsqrtf(var + LN_EPS) * ls[lane] + lb[lane];
  xg_new[(size_t)i * D + lane] = fmaxf(o, 0.0f);
}

// ---------------- fused cell layer -----------------------------------------
__global__ __launch_bounds__(256) void cell_layer_kernel(
    const int* __restrict__ rp_cc, const int* __restrict__ src_cc,
    const float* __restrict__ xc_old,
    const float* __restrict__ eps_cc, const float* __restrict__ W_cc,
    const float* __restrict__ b_cc,
    const float* __restrict__ ls, const float* __restrict__ lb,
    float* __restrict__ xc_new, int n) {
  int i = (int)(((size_t)blockIdx.x * blockDim.x + threadIdx.x) >> 6);
  int lane = threadIdx.x & 63;
  if (i >= n) return;
  float self = xc_old[(size_t)i * D + lane];
  float acc = 0.0f;
  int e0 = rp_cc[i], e1 = rp_cc[i + 1];
  for (int e = e0; e < e1; ++e)
    acc += xc_old[(size_t)src_cc[e] * D + lane];
  float h = (1.0f + eps_cc[0]) * self + acc;
  float gin = b_cc[lane];
#pragma unroll
  for (int k = 0; k < 64; ++k)
    gin = fmaf(__shfl(h, k), W_cc[k * 64 + lane], gin);
  float g = fmaxf(gin, 0.0f);
  float m = wave_sum64(g) * (1.0f / 64.0f);
  float d = g - m;
  float var = wave_sum64(d * d) * (1.0f / 64.0f);
  float o = d * rsqrtf(var + LN_EPS) * ls[lane] + lb[lane];
  xc_new[(size_t)i * D + lane] = fmaxf(o, 0.0f);
}

// ---------------- output head ----------------------------------------------
__global__ __launch_bounds__(256) void out_kernel(
    const float* __restrict__ xg, const float* __restrict__ W,
    const float* __restrict__ b, float* __restrict__ out, int n) {
  int r = blockIdx.x * 256 + threadIdx.x;
  if (r >= n) return;
  float a0 = b[0], a1 = b[1], a2 = b[2];
  const float* xr = xg + (size_t)r * D;
#pragma unroll
  for (int k = 0; k < 64; ++k) {
    float v = xr[k];
    a0 = fmaf(v, W[k * 3 + 0], a0);
    a1 = fmaf(v, W[k * 3 + 1], a1);
    a2 = fmaf(v, W[k * 3 + 2], a2);
  }
  float m = fmaxf(a0, fmaxf(a1, a2));
  float e0 = expf(a0 - m), e1 = expf(a1 - m), e2 = expf(a2 - m);
  float inv = 1.0f / (e0 + e1 + e2);
  out[(size_t)r * 3 + 0] = e0 * inv;
  out[(size_t)r * 3 + 1] = e1 * inv;
  out[(size_t)r * 3 + 2] = e2 * inv;
}

extern "C" void kernel_launch(void* const* d_in, const int* in_sizes, int n_in,
                              void* d_out, int out_size, void* d_ws, size_t ws_size,
                              hipStream_t stream) {
  const float* x_glom = (const float*)d_in[0];
  const float* x_cell = (const float*)d_in[1];
  const int*   ei_gg  = (const int*)d_in[2];
  const float* ew_gg  = (const float*)d_in[3];
  const int*   ei_cg  = (const int*)d_in[4];
  const int*   ei_cc  = (const int*)d_in[5];
  const float* W_in_g = (const float*)d_in[6];
  const float* b_in_g = (const float*)d_in[7];
  const float* lnig_s = (const float*)d_in[8];
  const float* lnig_b = (const float*)d_in[9];
  const float* W_in_c = (const float*)d_in[10];
  const float* b_in_c = (const float*)d_in[11];
  const float* lnic_s = (const float*)d_in[12];
  const float* lnic_b = (const float*)d_in[13];
  const float* W_outp = (const float*)d_in[34];
  const float* b_outp = (const float*)d_in[35];

  // ---- workspace layout (~98 MB) ----
  float* F = (float*)d_ws;
  size_t off = 0;
  float* xg0  = F + off; off += (size_t)NG * D;
  float* xg1  = F + off; off += (size_t)NG * D;
  float* xc0  = F + off; off += (size_t)NC * D;
  float* xc1  = F + off; off += (size_t)NC * D;
  float* dinv = F + off; off += NG;
  float* nrm_gg = F + off; off += EGG;
  int* I = (int*)(F + off);
  size_t io = 0;
  int* rp_gg  = I + io; io += NG + 1;
  int* rp_cg  = I + io; io += NG + 1;
  int* rp_cc  = I + io; io += NC + 1;
  int* cnt_gg = I + io; io += NG;   // reused as fill cursor
  int* cnt_cg = I + io; io += NG;
  int* cnt_cc = I + io; io += NC;
  int* src_gg = I + io; io += EGG;
  int* src_cg = I + io; io += ECG;
  int* src_cc = I + io; io += ECC;

  dim3 blk(256);
  auto wgrid = [](long long waves) { return dim3((unsigned)((waves + 3) / 4)); };
  auto egrid = [](long long e) { return dim3((unsigned)((e + 255) / 256)); };

  // ---- CSR build (edge structure shared by both layers) ----
  hipMemsetAsync(cnt_gg, 0, (2 * NG + NC) * sizeof(int), stream);  // cnt_* contiguous
  hipMemsetAsync(dinv, 0, NG * sizeof(float), stream);
  count_kernel<<<egrid(EGG), blk, 0, stream>>>(ei_gg, cnt_gg, EGG);
  count_kernel<<<egrid(ECG), blk, 0, stream>>>(ei_cg, cnt_cg, ECG);
  count_kernel<<<egrid(ECC), blk, 0, stream>>>(ei_cc, cnt_cc, ECC);
  deg_kernel<<<egrid(EGG), blk, 0, stream>>>(ei_gg, ew_gg, dinv);
  scan3_kernel<<<dim3(3), dim3(1024), 0, stream>>>(
      cnt_gg, rp_gg, NG, cnt_cg, rp_cg, NG, cnt_cc, rp_cc, NC);
  dinv_kernel<<<egrid(NG), blk, 0, stream>>>(dinv, NG);
  hipMemcpyAsync(cnt_gg, rp_gg, NG * sizeof(int), hipMemcpyDeviceToDevice, stream);
  hipMemcpyAsync(cnt_cg, rp_cg, NG * sizeof(int), hipMemcpyDeviceToDevice, stream);
  hipMemcpyAsync(cnt_cc, rp_cc, NC * sizeof(int), hipMemcpyDeviceToDevice, stream);
  fill_gg_kernel<<<egrid(EGG), blk, 0, stream>>>(ei_gg, ew_gg, dinv, cnt_gg, src_gg, nrm_gg);
  fill_gin_kernel<<<egrid(ECG), blk, 0, stream>>>(ei_cg, cnt_cg, src_cg, ECG);
  fill_gin_kernel<<<egrid(ECC), blk, 0, stream>>>(ei_cc, cnt_cc, src_cc, ECC);

  // ---- input FCs ----
  fc_in_kernel<<<wgrid(NG), blk, 0, stream>>>(x_glom, W_in_g, b_in_g, lnig_s, lnig_b, xg0, NG);
  fc_in_kernel<<<wgrid(NC), blk, 0, stream>>>(x_cell, W_in_c, b_in_c, lnic_s, lnic_b, xc0, NC);

  // ---- two hetero MP layers (double-buffered) ----
  float* xg_cur = xg0; float* xg_nxt = xg1;
  float* xc_cur = xc0; float* xc_nxt = xc1;
  for (int l = 0; l < 2; ++l) {
    const float* const* p = (const float* const*)(d_in + 14 + 10 * l);
    const float* W_gcn = p[0]; const float* b_gcn = p[1];
    const float* eps_cg = p[2]; const float* W_cg = p[3]; const float* b_cg = p[4];
    const float* eps_cc = p[5]; const float* W_cc = p[6]; const float* b_cc = p[7];
    const float* ln_s = p[8]; const float* ln_b = p[9];

    glom_layer_kernel<<<wgrid(NG), blk, 0, stream>>>(
        rp_gg, src_gg, nrm_gg, rp_cg, src_cg, xg_cur, xc_cur, dinv,
        W_gcn, b_gcn, eps_cg, W_cg, b_cg, ln_s, ln_b, xg_nxt, NG);
    cell_layer_kernel<<<wgrid(NC), blk, 0, stream>>>(
        rp_cc, src_cc, xc_cur, eps_cc, W_cc, b_cc, ln_s, ln_b, xc_nxt, NC);

    float* t;
    t = xg_cur; xg_cur = xg_nxt; xg_nxt = t;
    t = xc_cur; xc_cur = xc_nxt; xc_nxt = t;
  }

  out_kernel<<<egrid(NG), blk, 0, stream>>>(xg_cur, W_outp, b_outp, (float*)d_out, NG);
}

// Round 3
// 1497.013 us; speedup vs baseline: 1.5860x; 1.2447x over previous
//
#include <hip/hip_runtime.h>

#define NG 50000
#define NC 100000
#define DIN 128
#define D 64
#define EGG 800000
#define ECG 1600000
#define ECC 1600000
#define LN_EPS 1e-5f

__device__ __forceinline__ float wave_sum64(float v) {
#pragma unroll
  for (int off = 32; off > 0; off >>= 1) v += __shfl_xor(v, off);
  return v;
}

// Gather-accumulate over a CSR range with batched index preload + 4-way MLP.
// acc += sum_e w_e * tab[src_e * 64 + lane]   (w_e = 1 if nrm == nullptr)
__device__ __forceinline__ float csr_gather(
    const int* __restrict__ src, const float* __restrict__ nrm,
    const float* __restrict__ tab, int e0, int e1, int lane) {
  float a0 = 0.0f, a1 = 0.0f, a2 = 0.0f, a3 = 0.0f;
  for (int base = e0; base < e1; base += 64) {
    int cnt = e1 - base; if (cnt > 64) cnt = 64;
    int sidx = 0; float snrm = 1.0f;
    if (base + lane < e1) {
      sidx = src[base + lane];
      if (nrm) snrm = nrm[base + lane];
    }
    int j = 0;
    for (; j + 4 <= cnt; j += 4) {
      int s0 = __shfl(sidx, j),     s1 = __shfl(sidx, j + 1);
      int s2 = __shfl(sidx, j + 2), s3 = __shfl(sidx, j + 3);
      float n0 = 1.0f, n1 = 1.0f, n2 = 1.0f, n3 = 1.0f;
      if (nrm) {
        n0 = __shfl(snrm, j);     n1 = __shfl(snrm, j + 1);
        n2 = __shfl(snrm, j + 2); n3 = __shfl(snrm, j + 3);
      }
      a0 = fmaf(n0, tab[(size_t)s0 * D + lane], a0);
      a1 = fmaf(n1, tab[(size_t)s1 * D + lane], a1);
      a2 = fmaf(n2, tab[(size_t)s2 * D + lane], a2);
      a3 = fmaf(n3, tab[(size_t)s3 * D + lane], a3);
    }
    for (; j < cnt; ++j) {
      int s = __shfl(sidx, j);
      float nv = nrm ? __shfl(snrm, j) : 1.0f;
      a0 = fmaf(nv, tab[(size_t)s * D + lane], a0);
    }
  }
  return (a0 + a1) + (a2 + a3);
}

// ---------------- dense input FC: y = relu(LN(x @ W + b)), wave per row ----
__global__ __launch_bounds__(256) void fc_in_kernel(
    const float* __restrict__ x, const float* __restrict__ W,
    const float* __restrict__ b, const float* __restrict__ s,
    const float* __restrict__ beta, float* __restrict__ y, int n) {
  int wid = (int)(((size_t)blockIdx.x * blockDim.x + threadIdx.x) >> 6);
  int lane = threadIdx.x & 63;
  if (wid >= n) return;
  const float* xr = x + (size_t)wid * DIN;
  float v0 = xr[lane];
  float v1 = xr[64 + lane];
  float acc = b[lane];
#pragma unroll
  for (int k = 0; k < 64; ++k)
    acc = fmaf(__shfl(v0, k), W[k * 64 + lane], acc);
#pragma unroll
  for (int k = 0; k < 64; ++k)
    acc = fmaf(__shfl(v1, k), W[(k + 64) * 64 + lane], acc);
  float m = wave_sum64(acc) * (1.0f / 64.0f);
  float d = acc - m;
  float var = wave_sum64(d * d) * (1.0f / 64.0f);
  float o = d * rsqrtf(var + LN_EPS) * s[lane] + beta[lane];
  y[(size_t)wid * D + lane] = fmaxf(o, 0.0f);
}

// ---------------- CSR build ------------------------------------------------
// one pass over all three edge sets: dst counts + weighted degree for gg
__global__ __launch_bounds__(256) void count_all_kernel(
    const int* __restrict__ ei_gg, const float* __restrict__ ew_gg,
    const int* __restrict__ ei_cg, const int* __restrict__ ei_cc,
    int* __restrict__ cnt_gg, float* __restrict__ deg,
    int* __restrict__ cnt_cg, int* __restrict__ cnt_cc) {
  int e = blockIdx.x * 256 + threadIdx.x;
  if (e < EGG) {
    int c = ei_gg[EGG + e];
    atomicAdd(&cnt_gg[c], 1);
    atomicAdd(&deg[c], ew_gg[e]);
  }
  if (e < ECG) atomicAdd(&cnt_cg[ei_cg[ECG + e]], 1);
  if (e < ECC) atomicAdd(&cnt_cc[ei_cc[ECC + e]], 1);
}

__global__ __launch_bounds__(256) void dinv_kernel(float* __restrict__ deg, int n) {
  int i = blockIdx.x * 256 + threadIdx.x;
  if (i < n) deg[i] = rsqrtf(deg[i] + 1.0f);
}

// three exclusive prefix sums (one block each): rp[0..n] from cnt[0..n-1]
__global__ __launch_bounds__(1024) void scan3_kernel(
    const int* __restrict__ c0, int* __restrict__ r0, int n0,
    const int* __restrict__ c1, int* __restrict__ r1, int n1,
    const int* __restrict__ c2, int* __restrict__ r2, int n2) {
  const int* cnt; int* rp; int n;
  if (blockIdx.x == 0) { cnt = c0; rp = r0; n = n0; }
  else if (blockIdx.x == 1) { cnt = c1; rp = r1; n = n1; }
  else { cnt = c2; rp = r2; n = n2; }
  __shared__ int sh[1024];
  __shared__ int carry_sh;
  int tid = threadIdx.x;
  if (tid == 0) carry_sh = 0;
  __syncthreads();
  for (int base = 0; base < n; base += 1024) {
    int i = base + tid;
    int v = (i < n) ? cnt[i] : 0;
    sh[tid] = v;
    __syncthreads();
#pragma unroll
    for (int off = 1; off < 1024; off <<= 1) {
      int t = (tid >= off) ? sh[tid - off] : 0;
      __syncthreads();
      sh[tid] += t;
      __syncthreads();
    }
    int carry = carry_sh;
    if (i < n) rp[i] = carry + sh[tid] - v;
    __syncthreads();
    if (tid == 1023) carry_sh = carry + sh[1023];
    __syncthreads();
  }
  if (tid == 0) rp[n] = carry_sh;
}

// fill: pos = cur[dst]++; src[pos] = src_node  (GIN relations)
__global__ __launch_bounds__(256) void fill_gin_kernel(
    const int* __restrict__ ei, int* __restrict__ cur,
    int* __restrict__ src, int E) {
  int e = blockIdx.x * 256 + threadIdx.x;
  if (e >= E) return;
  int c = ei[E + e];
  int pos = atomicAdd(&cur[c], 1);
  src[pos] = ei[e];
}

// fill for GCN: also precompute norm = dinv[r]*ew*dinv[c]
__global__ __launch_bounds__(256) void fill_gg_kernel(
    const int* __restrict__ ei, const float* __restrict__ ew,
    const float* __restrict__ dinv, int* __restrict__ cur,
    int* __restrict__ src, float* __restrict__ nrm) {
  int e = blockIdx.x * 256 + threadIdx.x;
  if (e >= EGG) return;
  int r = ei[e];
  int c = ei[EGG + e];
  int pos = atomicAdd(&cur[c], 1);
  src[pos] = r;
  nrm[pos] = dinv[r] * ew[e] * dinv[c];
}

// ---------------- fused glom layer -----------------------------------------
__global__ __launch_bounds__(256) void glom_layer_kernel(
    const int* __restrict__ rp_gg, const int* __restrict__ src_gg,
    const float* __restrict__ nrm_gg,
    const int* __restrict__ rp_cg, const int* __restrict__ src_cg,
    const float* __restrict__ xg_old, const float* __restrict__ xc_old,
    const float* __restrict__ dinv,
    const float* __restrict__ W_gcn, const float* __restrict__ b_gcn,
    const float* __restrict__ eps_cg, const float* __restrict__ W_cg,
    const float* __restrict__ b_cg,
    const float* __restrict__ ls, const float* __restrict__ lb,
    float* __restrict__ xg_new, int n) {
  int i = (int)(((size_t)blockIdx.x * blockDim.x + threadIdx.x) >> 6);
  int lane = threadIdx.x & 63;
  if (i >= n) return;
  float self = xg_old[(size_t)i * D + lane];
  float di = dinv[i];
  float accG = di * di * self
             + csr_gather(src_gg, nrm_gg, xg_old, rp_gg[i], rp_gg[i + 1], lane);
  float accC = csr_gather(src_cg, nullptr, xc_old, rp_cg[i], rp_cg[i + 1], lane);
  float gcn = b_gcn[lane];
#pragma unroll
  for (int k = 0; k < 64; ++k)
    gcn = fmaf(__shfl(accG, k), W_gcn[k * 64 + lane], gcn);
  float h = (1.0f + eps_cg[0]) * self + accC;
  float gin = b_cg[lane];
#pragma unroll
  for (int k = 0; k < 64; ++k)
    gin = fmaf(__shfl(h, k), W_cg[k * 64 + lane], gin);
  float g = gcn + fmaxf(gin, 0.0f);
  float m = wave_sum64(g) * (1.0f / 64.0f);
  float d = g - m;
  float var = wave_sum64(d * d) * (1.0f / 64.0f);
  float o = d * rsqrtf(var + LN_EPS) * ls[lane] + lb[lane];
  xg_new[(size_t)i * D + lane] = fmaxf(o, 0.0f);
}

// ---------------- fused cell layer -----------------------------------------
__global__ __launch_bounds__(256) void cell_layer_kernel(
    const int* __restrict__ rp_cc, const int* __restrict__ src_cc,
    const float* __restrict__ xc_old,
    const float* __restrict__ eps_cc, const float* __restrict__ W_cc,
    const float* __restrict__ b_cc,
    const float* __restrict__ ls, const float* __restrict__ lb,
    float* __restrict__ xc_new, int n) {
  int i = (int)(((size_t)blockIdx.x * blockDim.x + threadIdx.x) >> 6);
  int lane = threadIdx.x & 63;
  if (i >= n) return;
  float self = xc_old[(size_t)i * D + lane];
  float acc = csr_gather(src_cc, nullptr, xc_old, rp_cc[i], rp_cc[i + 1], lane);
  float h = (1.0f + eps_cc[0]) * self + acc;
  float gin = b_cc[lane];
#pragma unroll
  for (int k = 0; k < 64; ++k)
    gin = fmaf(__shfl(h, k), W_cc[k * 64 + lane], gin);
  float g = fmaxf(gin, 0.0f);
  float m = wave_sum64(g) * (1.0f / 64.0f);
  float d = g - m;
  float var = wave_sum64(d * d) * (1.0f / 64.0f);
  float o = d * rsqrtf(var + LN_EPS) * ls[lane] + lb[lane];
  xc_new[(size_t)i * D + lane] = fmaxf(o, 0.0f);
}

// ---------------- output head: wave per row --------------------------------
__global__ __launch_bounds__(256) void out_kernel(
    const float* __restrict__ xg, const float* __restrict__ W,
    const float* __restrict__ b, float* __restrict__ out, int n) {
  int wid = (int)(((size_t)blockIdx.x * blockDim.x + threadIdx.x) >> 6);
  int lane = threadIdx.x & 63;
  if (wid >= n) return;
  float v = xg[(size_t)wid * D + lane];
  float a0 = wave_sum64(v * W[lane * 3 + 0]) + b[0];
  float a1 = wave_sum64(v * W[lane * 3 + 1]) + b[1];
  float a2 = wave_sum64(v * W[lane * 3 + 2]) + b[2];
  float m = fmaxf(a0, fmaxf(a1, a2));
  float e0 = expf(a0 - m), e1 = expf(a1 - m), e2 = expf(a2 - m);
  float inv = 1.0f / (e0 + e1 + e2);
  if (lane == 0) {
    out[(size_t)wid * 3 + 0] = e0 * inv;
    out[(size_t)wid * 3 + 1] = e1 * inv;
    out[(size_t)wid * 3 + 2] = e2 * inv;
  }
}

extern "C" void kernel_launch(void* const* d_in, const int* in_sizes, int n_in,
                              void* d_out, int out_size, void* d_ws, size_t ws_size,
                              hipStream_t stream) {
  const float* x_glom = (const float*)d_in[0];
  const float* x_cell = (const float*)d_in[1];
  const int*   ei_gg  = (const int*)d_in[2];
  const float* ew_gg  = (const float*)d_in[3];
  const int*   ei_cg  = (const int*)d_in[4];
  const int*   ei_cc  = (const int*)d_in[5];
  const float* W_in_g = (const float*)d_in[6];
  const float* b_in_g = (const float*)d_in[7];
  const float* lnig_s = (const float*)d_in[8];
  const float* lnig_b = (const float*)d_in[9];
  const float* W_in_c = (const float*)d_in[10];
  const float* b_in_c = (const float*)d_in[11];
  const float* lnic_s = (const float*)d_in[12];
  const float* lnic_b = (const float*)d_in[13];
  const float* W_outp = (const float*)d_in[34];
  const float* b_outp = (const float*)d_in[35];

  // ---- workspace layout (~98 MB) ----
  float* F = (float*)d_ws;
  size_t off = 0;
  float* xg0  = F + off; off += (size_t)NG * D;
  float* xg1  = F + off; off += (size_t)NG * D;
  float* xc0  = F + off; off += (size_t)NC * D;
  float* xc1  = F + off; off += (size_t)NC * D;
  float* dinv = F + off; off += NG;
  float* nrm_gg = F + off; off += EGG;
  int* I = (int*)(F + off);
  size_t io = 0;
  int* rp_gg  = I + io; io += NG + 1;
  int* rp_cg  = I + io; io += NG + 1;
  int* rp_cc  = I + io; io += NC + 1;
  int* cnt_gg = I + io; io += NG;   // reused as fill cursor
  int* cnt_cg = I + io; io += NG;
  int* cnt_cc = I + io; io += NC;
  int* src_gg = I + io; io += EGG;
  int* src_cg = I + io; io += ECG;
  int* src_cc = I + io; io += ECC;

  dim3 blk(256);
  auto wgrid = [](long long waves) { return dim3((unsigned)((waves + 3) / 4)); };
  auto egrid = [](long long e) { return dim3((unsigned)((e + 255) / 256)); };

  // ---- CSR build (edge structure shared by both layers) ----
  hipMemsetAsync(cnt_gg, 0, (2 * NG + NC) * sizeof(int), stream);  // cnt_* contiguous
  hipMemsetAsync(dinv, 0, NG * sizeof(float), stream);
  count_all_kernel<<<egrid(ECG), blk, 0, stream>>>(
      ei_gg, ew_gg, ei_cg, ei_cc, cnt_gg, dinv, cnt_cg, cnt_cc);
  scan3_kernel<<<dim3(3), dim3(1024), 0, stream>>>(
      cnt_gg, rp_gg, NG, cnt_cg, rp_cg, NG, cnt_cc, rp_cc, NC);
  dinv_kernel<<<egrid(NG), blk, 0, stream>>>(dinv, NG);
  hipMemcpyAsync(cnt_gg, rp_gg, NG * sizeof(int), hipMemcpyDeviceToDevice, stream);
  hipMemcpyAsync(cnt_cg, rp_cg, NG * sizeof(int), hipMemcpyDeviceToDevice, stream);
  hipMemcpyAsync(cnt_cc, rp_cc, NC * sizeof(int), hipMemcpyDeviceToDevice, stream);
  fill_gg_kernel<<<egrid(EGG), blk, 0, stream>>>(ei_gg, ew_gg, dinv, cnt_gg, src_gg, nrm_gg);
  fill_gin_kernel<<<egrid(ECG), blk, 0, stream>>>(ei_cg, cnt_cg, src_cg, ECG);
  fill_gin_kernel<<<egrid(ECC), blk, 0, stream>>>(ei_cc, cnt_cc, src_cc, ECC);

  // ---- input FCs ----
  fc_in_kernel<<<wgrid(NG), blk, 0, stream>>>(x_glom, W_in_g, b_in_g, lnig_s, lnig_b, xg0, NG);
  fc_in_kernel<<<wgrid(NC), blk, 0, stream>>>(x_cell, W_in_c, b_in_c, lnic_s, lnic_b, xc0, NC);

  // ---- two hetero MP layers (double-buffered) ----
  float* xg_cur = xg0; float* xg_nxt = xg1;
  float* xc_cur = xc0; float* xc_nxt = xc1;
  for (int l = 0; l < 2; ++l) {
    const float* const* p = (const float* const*)(d_in + 14 + 10 * l);
    const float* W_gcn = p[0]; const float* b_gcn = p[1];
    const float* eps_cg = p[2]; const float* W_cg = p[3]; const float* b_cg = p[4];
    const float* eps_cc = p[5]; const float* W_cc = p[6]; const float* b_cc = p[7];
    const float* ln_s = p[8]; const float* ln_b = p[9];

    glom_layer_kernel<<<wgrid(NG), blk, 0, stream>>>(
        rp_gg, src_gg, nrm_gg, rp_cg, src_cg, xg_cur, xc_cur, dinv,
        W_gcn, b_gcn, eps_cg, W_cg, b_cg, ln_s, ln_b, xg_nxt, NG);
    cell_layer_kernel<<<wgrid(NC), blk, 0, stream>>>(
        rp_cc, src_cc, xc_cur, eps_cc, W_cc, b_cc, ln_s, ln_b, xc_nxt, NC);

    float* t;
    t = xg_cur; xg_cur = xg_nxt; xg_nxt = t;
    t = xc_cur; xc_cur = xc_nxt; xc_nxt = t;
  }

  out_kernel<<<wgrid(NG), blk, 0, stream>>>(xg_cur, W_outp, b_outp, (float*)d_out, NG);
}

// Round 4
// 1080.027 us; speedup vs baseline: 2.1983x; 1.3861x over previous
//
#include <hip/hip_runtime.h>

#define NG 50000
#define NC 100000
#define DIN 128
#define D 64
#define EGG 800000
#define ECG 1600000
#define ECC 1600000
#define LN_EPS 1e-5f

#define SCAN_N (2 * NG + NC)            // 200000 concatenated counters
#define SCAN_TPB 256
#define SCAN_PER_THREAD 8
#define SCAN_TILE (SCAN_TPB * SCAN_PER_THREAD)   // 2048
#define SCAN_NBLK ((SCAN_N + SCAN_TILE - 1) / SCAN_TILE)  // 98

__device__ __forceinline__ float wave_sum64(float v) {
#pragma unroll
  for (int off = 32; off > 0; off >>= 1) v += __shfl_xor(v, off);
  return v;
}

// Gather-accumulate over a CSR range: batched 64-wide index preload, 8-way
// unrolled MLP, weight-masked tail (w=0 for lanes past the segment end).
// acc += sum_e w_e * tab[src_e * 64 + lane]    (w_e = nrm[e] or 1.0)
__device__ __forceinline__ float csr_gather(
    const int* __restrict__ src, const float* __restrict__ nrm,
    const float* __restrict__ tab, int e0, int e1, int lane) {
  float a0 = 0.f, a1 = 0.f, a2 = 0.f, a3 = 0.f;
  float a4 = 0.f, a5 = 0.f, a6 = 0.f, a7 = 0.f;
  for (int base = e0; base < e1; base += 64) {
    int cnt = e1 - base; if (cnt > 64) cnt = 64;
    int sidx = 0; float w = 0.0f;
    if (lane < cnt) {
      sidx = src[base + lane];
      w = nrm ? nrm[base + lane] : 1.0f;
    }
    int jend = (cnt + 7) & ~7;
    for (int j = 0; j < jend; j += 8) {
      int s0 = __shfl(sidx, j + 0), s1 = __shfl(sidx, j + 1);
      int s2 = __shfl(sidx, j + 2), s3 = __shfl(sidx, j + 3);
      int s4 = __shfl(sidx, j + 4), s5 = __shfl(sidx, j + 5);
      int s6 = __shfl(sidx, j + 6), s7 = __shfl(sidx, j + 7);
      float n0 = __shfl(w, j + 0), n1 = __shfl(w, j + 1);
      float n2 = __shfl(w, j + 2), n3 = __shfl(w, j + 3);
      float n4 = __shfl(w, j + 4), n5 = __shfl(w, j + 5);
      float n6 = __shfl(w, j + 6), n7 = __shfl(w, j + 7);
      a0 = fmaf(n0, tab[(size_t)s0 * D + lane], a0);
      a1 = fmaf(n1, tab[(size_t)s1 * D + lane], a1);
      a2 = fmaf(n2, tab[(size_t)s2 * D + lane], a2);
      a3 = fmaf(n3, tab[(size_t)s3 * D + lane], a3);
      a4 = fmaf(n4, tab[(size_t)s4 * D + lane], a4);
      a5 = fmaf(n5, tab[(size_t)s5 * D + lane], a5);
      a6 = fmaf(n6, tab[(size_t)s6 * D + lane], a6);
      a7 = fmaf(n7, tab[(size_t)s7 * D + lane], a7);
    }
  }
  return ((a0 + a1) + (a2 + a3)) + ((a4 + a5) + (a6 + a7));
}

// ---------------- dense input FC: y = relu(LN(x @ W + b)), wave per row ----
__global__ __launch_bounds__(256) void fc_in_kernel(
    const float* __restrict__ x, const float* __restrict__ W,
    const float* __restrict__ b, const float* __restrict__ s,
    const float* __restrict__ beta, float* __restrict__ y, int n) {
  int wid = (int)(((size_t)blockIdx.x * blockDim.x + threadIdx.x) >> 6);
  int lane = threadIdx.x & 63;
  if (wid >= n) return;
  const float* xr = x + (size_t)wid * DIN;
  float v0 = xr[lane];
  float v1 = xr[64 + lane];
  float acc = b[lane];
#pragma unroll
  for (int k = 0; k < 64; ++k)
    acc = fmaf(__shfl(v0, k), W[k * 64 + lane], acc);
#pragma unroll
  for (int k = 0; k < 64; ++k)
    acc = fmaf(__shfl(v1, k), W[(k + 64) * 64 + lane], acc);
  float m = wave_sum64(acc) * (1.0f / 64.0f);
  float d = acc - m;
  float var = wave_sum64(d * d) * (1.0f / 64.0f);
  float o = d * rsqrtf(var + LN_EPS) * s[lane] + beta[lane];
  y[(size_t)wid * D + lane] = fmaxf(o, 0.0f);
}

// ---------------- CSR build: single atomic pass ----------------------------
// pos[e] = old count of this edge's (relation-offset) destination key.
__global__ __launch_bounds__(256) void passA_kernel(
    const int* __restrict__ ei_gg, const int* __restrict__ ei_cg,
    const int* __restrict__ ei_cc, int* __restrict__ cnt,
    int* __restrict__ pos_gg, int* __restrict__ pos_cg,
    int* __restrict__ pos_cc) {
  int e = blockIdx.x * 256 + threadIdx.x;
  if (e < EGG) pos_gg[e] = atomicAdd(&cnt[ei_gg[EGG + e]], 1);
  if (e < ECG) pos_cg[e] = atomicAdd(&cnt[NG + ei_cg[ECG + e]], 1);
  if (e < ECC) pos_cc[e] = atomicAdd(&cnt[2 * NG + ei_cc[ECC + e]], 1);
}

// ---------------- hierarchical exclusive scan over cnt[0..SCAN_N) ----------
__global__ __launch_bounds__(SCAN_TPB) void scan_blocksum_kernel(
    const int* __restrict__ cnt, int* __restrict__ bsum) {
  __shared__ int sh[SCAN_TPB / 64];
  int t = threadIdx.x;
  int base = blockIdx.x * SCAN_TILE + t * SCAN_PER_THREAD;
  int s = 0;
#pragma unroll
  for (int k = 0; k < SCAN_PER_THREAD; ++k) {
    int i = base + k;
    if (i < SCAN_N) s += cnt[i];
  }
#pragma unroll
  for (int off = 32; off > 0; off >>= 1) s += __shfl_xor(s, off);
  if ((t & 63) == 0) sh[t >> 6] = s;
  __syncthreads();
  if (t == 0) {
    int tot = 0;
#pragma unroll
    for (int w = 0; w < SCAN_TPB / 64; ++w) tot += sh[w];
    bsum[blockIdx.x] = tot;
  }
}

__global__ void scan_bsum_kernel(int* __restrict__ bsum, int* __restrict__ S) {
  if (threadIdx.x == 0) {
    int acc = 0;
    for (int b = 0; b < SCAN_NBLK; ++b) {
      int v = bsum[b]; bsum[b] = acc; acc += v;
    }
    S[SCAN_N] = acc;  // total edge count
  }
}

__global__ __launch_bounds__(SCAN_TPB) void scan_final_kernel(
    const int* __restrict__ cnt, const int* __restrict__ bsum,
    int* __restrict__ S) {
  int t = threadIdx.x;
  int lane = t & 63;
  int base = blockIdx.x * SCAN_TILE + t * SCAN_PER_THREAD;
  int v[SCAN_PER_THREAD];
  int s = 0;
#pragma unroll
  for (int k = 0; k < SCAN_PER_THREAD; ++k) {
    int i = base + k;
    v[k] = (i < SCAN_N) ? cnt[i] : 0;
    s += v[k];
  }
  int sc = s;  // inclusive wave scan of per-thread sums
#pragma unroll
  for (int off = 1; off < 64; off <<= 1) {
    int u = __shfl_up(sc, off);
    if (lane >= off) sc += u;
  }
  __shared__ int wsum[SCAN_TPB / 64];
  if (lane == 63) wsum[t >> 6] = sc;
  __syncthreads();
  int wbase = 0;
  for (int w = 0; w < (t >> 6); ++w) wbase += wsum[w];
  int ex = bsum[blockIdx.x] + wbase + (sc - s);
#pragma unroll
  for (int k = 0; k < SCAN_PER_THREAD; ++k) {
    int i = base + k;
    if (i < SCAN_N) S[i] = ex;
    ex += v[k];
  }
}

// ---------------- atomic-free scatter into the unified src buffer ----------
__global__ __launch_bounds__(256) void scatter_kernel(
    const int* __restrict__ ei_gg, const float* __restrict__ ew_gg,
    const int* __restrict__ ei_cg, const int* __restrict__ ei_cc,
    const int* __restrict__ S, const int* __restrict__ pos_gg,
    const int* __restrict__ pos_cg, const int* __restrict__ pos_cc,
    int* __restrict__ srcbuf, float* __restrict__ ewp) {
  int e = blockIdx.x * 256 + threadIdx.x;
  if (e < EGG) {
    int d = ei_gg[EGG + e];
    int p = S[d] + pos_gg[e];
    srcbuf[p] = ei_gg[e];
    ewp[p] = ew_gg[e];
  }
  if (e < ECG) {
    int d = ei_cg[ECG + e];
    int p = S[NG + d] + pos_cg[e];
    srcbuf[p] = ei_cg[e];
  }
  if (e < ECC) {
    int d = ei_cc[ECC + e];
    int p = S[2 * NG + d] + pos_cc[e];
    srcbuf[p] = ei_cc[e];
  }
}

// dinv[i] = rsqrt(1 + sum of permuted edge weights over segment)
__global__ __launch_bounds__(256) void deg_kernel(
    const int* __restrict__ S, const float* __restrict__ ewp,
    float* __restrict__ dinv) {
  int i = (int)(((size_t)blockIdx.x * blockDim.x + threadIdx.x) >> 6);
  int lane = threadIdx.x & 63;
  if (i >= NG) return;
  int e0 = S[i], e1 = S[i + 1];
  float s = 0.0f;
  for (int e = e0 + lane; e < e1; e += 64) s += ewp[e];
  s = wave_sum64(s);
  if (lane == 0) dinv[i] = rsqrtf(s + 1.0f);
}

// nrm[e] = dinv[src] * ew * dinv[dst]
__global__ __launch_bounds__(256) void nrm_kernel(
    const int* __restrict__ S, const int* __restrict__ srcbuf,
    const float* __restrict__ ewp, const float* __restrict__ dinv,
    float* __restrict__ nrm) {
  int i = (int)(((size_t)blockIdx.x * blockDim.x + threadIdx.x) >> 6);
  int lane = threadIdx.x & 63;
  if (i >= NG) return;
  float di = dinv[i];
  int e0 = S[i], e1 = S[i + 1];
  for (int e = e0 + lane; e < e1; e += 64)
    nrm[e] = dinv[srcbuf[e]] * ewp[e] * di;
}

// ---------------- fused glom layer -----------------------------------------
__global__ __launch_bounds__(256) void glom_layer_kernel(
    const int* __restrict__ rp_gg, const int* __restrict__ rp_cg,
    const int* __restrict__ srcbuf, const float* __restrict__ nrm_gg,
    const float* __restrict__ xg_old, const float* __restrict__ xc_old,
    const float* __restrict__ dinv,
    const float* __restrict__ W_gcn, const float* __restrict__ b_gcn,
    const float* __restrict__ eps_cg, const float* __restrict__ W_cg,
    const float* __restrict__ b_cg,
    const float* __restrict__ ls, const float* __restrict__ lb,
    float* __restrict__ xg_new, int n) {
  int i = (int)(((size_t)blockIdx.x * blockDim.x + threadIdx.x) >> 6);
  int lane = threadIdx.x & 63;
  if (i >= n) return;
  float self = xg_old[(size_t)i * D + lane];
  float di = dinv[i];
  float accG = di * di * self
             + csr_gather(srcbuf, nrm_gg, xg_old, rp_gg[i], rp_gg[i + 1], lane);
  float accC = csr_gather(srcbuf, nullptr, xc_old, rp_cg[i], rp_cg[i + 1], lane);
  float gcn = b_gcn[lane];
#pragma unroll
  for (int k = 0; k < 64; ++k)
    gcn = fmaf(__shfl(accG, k), W_gcn[k * 64 + lane], gcn);
  float h = (1.0f + eps_cg[0]) * self + accC;
  float gin = b_cg[lane];
#pragma unroll
  for (int k = 0; k < 64; ++k)
    gin = fmaf(__shfl(h, k), W_cg[k * 64 + lane], gin);
  float g = gcn + fmaxf(gin, 0.0f);
  float m = wave_sum64(g) * (1.0f / 64.0f);
  float d = g - m;
  float var = wave_sum64(d * d) * (1.0f / 64.0f);
  float o = d * rsqrtf(var + LN_EPS) * ls[lane] + lb[lane];
  xg_new[(size_t)i * D + lane] = fmaxf(o, 0.0f);
}

// ---------------- fused cell layer -----------------------------------------
__global__ __launch_bounds__(256) void cell_layer_kernel(
    const int* __restrict__ rp_cc, const int* __restrict__ srcbuf,
    const float* __restrict__ xc_old,
    const float* __restrict__ eps_cc, const float* __restrict__ W_cc,
    const float* __restrict__ b_cc,
    const float* __restrict__ ls, const float* __restrict__ lb,
    float* __restrict__ xc_new, int n) {
  int i = (int)(((size_t)blockIdx.x * blockDim.x + threadIdx.x) >> 6);
  int lane = threadIdx.x & 63;
  if (i >= n) return;
  float self = xc_old[(size_t)i * D + lane];
  float acc = csr_gather(srcbuf, nullptr, xc_old, rp_cc[i], rp_cc[i + 1], lane);
  float h = (1.0f + eps_cc[0]) * self + acc;
  float gin = b_cc[lane];
#pragma unroll
  for (int k = 0; k < 64; ++k)
    gin = fmaf(__shfl(h, k), W_cc[k * 64 + lane], gin);
  float g = fmaxf(gin, 0.0f);
  float m = wave_sum64(g) * (1.0f / 64.0f);
  float d = g - m;
  float var = wave_sum64(d * d) * (1.0f / 64.0f);
  float o = d * rsqrtf(var + LN_EPS) * ls[lane] + lb[lane];
  xc_new[(size_t)i * D + lane] = fmaxf(o, 0.0f);
}

// ---------------- output head: wave per row --------------------------------
__global__ __launch_bounds__(256) void out_kernel(
    const float* __restrict__ xg, const float* __restrict__ W,
    const float* __restrict__ b, float* __restrict__ out, int n) {
  int wid = (int)(((size_t)blockIdx.x * blockDim.x + threadIdx.x) >> 6);
  int lane = threadIdx.x & 63;
  if (wid >= n) return;
  float v = xg[(size_t)wid * D + lane];
  float a0 = wave_sum64(v * W[lane * 3 + 0]) + b[0];
  float a1 = wave_sum64(v * W[lane * 3 + 1]) + b[1];
  float a2 = wave_sum64(v * W[lane * 3 + 2]) + b[2];
  float m = fmaxf(a0, fmaxf(a1, a2));
  float e0 = expf(a0 - m), e1 = expf(a1 - m), e2 = expf(a2 - m);
  float inv = 1.0f / (e0 + e1 + e2);
  if (lane == 0) {
    out[(size_t)wid * 3 + 0] = e0 * inv;
    out[(size_t)wid * 3 + 1] = e1 * inv;
    out[(size_t)wid * 3 + 2] = e2 * inv;
  }
}

extern "C" void kernel_launch(void* const* d_in, const int* in_sizes, int n_in,
                              void* d_out, int out_size, void* d_ws, size_t ws_size,
                              hipStream_t stream) {
  const float* x_glom = (const float*)d_in[0];
  const float* x_cell = (const float*)d_in[1];
  const int*   ei_gg  = (const int*)d_in[2];
  const float* ew_gg  = (const float*)d_in[3];
  const int*   ei_cg  = (const int*)d_in[4];
  const int*   ei_cc  = (const int*)d_in[5];
  const float* W_in_g = (const float*)d_in[6];
  const float* b_in_g = (const float*)d_in[7];
  const float* lnig_s = (const float*)d_in[8];
  const float* lnig_b = (const float*)d_in[9];
  const float* W_in_c = (const float*)d_in[10];
  const float* b_in_c = (const float*)d_in[11];
  const float* lnic_s = (const float*)d_in[12];
  const float* lnic_b = (const float*)d_in[13];
  const float* W_outp = (const float*)d_in[34];
  const float* b_outp = (const float*)d_in[35];

  // ---- workspace layout (~98 MB) ----
  float* F = (float*)d_ws;
  size_t off = 0;
  float* xg0  = F + off; off += (size_t)NG * D;   // 3.2M floats
  float* xg1  = F + off; off += (size_t)NG * D;
  float* xc0  = F + off; off += (size_t)NC * D;   // 6.4M
  float* xc1  = F + off; off += (size_t)NC * D;
  float* dinv = F + off; off += NG;
  float* nrm  = F + off; off += EGG;              // GCN norms (absolute idx)
  int* I = (int*)(F + off);
  size_t io = 0;
  int* cnt  = I + io; io += SCAN_N;
  int* S    = I + io; io += SCAN_N + 1;
  int* bsum = I + io; io += SCAN_NBLK;
  int* srcbuf = I + io; io += (EGG + ECG + ECC);  // unified, absolute offsets
  // transient (dead before fc_in writes xg0/xg1): pos arrays + permuted ew
  int* pos_gg = (int*)xg0;
  int* pos_cg = pos_gg + EGG;
  int* pos_cc = pos_cg + ECG;
  float* ewp  = (float*)(pos_cc + ECC);           // still inside xg0+xg1 region

  dim3 blk(256);
  auto wgrid = [](long long waves) { return dim3((unsigned)((waves + 3) / 4)); };
  auto egrid = [](long long e) { return dim3((unsigned)((e + 255) / 256)); };

  // ---- CSR build: 1 atomic pass + hierarchical scan + atomic-free scatter --
  hipMemsetAsync(cnt, 0, SCAN_N * sizeof(int), stream);
  passA_kernel<<<egrid(ECG), blk, 0, stream>>>(
      ei_gg, ei_cg, ei_cc, cnt, pos_gg, pos_cg, pos_cc);
  scan_blocksum_kernel<<<dim3(SCAN_NBLK), dim3(SCAN_TPB), 0, stream>>>(cnt, bsum);
  scan_bsum_kernel<<<dim3(1), dim3(64), 0, stream>>>(bsum, S);
  scan_final_kernel<<<dim3(SCAN_NBLK), dim3(SCAN_TPB), 0, stream>>>(cnt, bsum, S);
  scatter_kernel<<<egrid(ECG), blk, 0, stream>>>(
      ei_gg, ew_gg, ei_cg, ei_cc, S, pos_gg, pos_cg, pos_cc, srcbuf, ewp);
  deg_kernel<<<wgrid(NG), blk, 0, stream>>>(S, ewp, dinv);
  nrm_kernel<<<wgrid(NG), blk, 0, stream>>>(S, srcbuf, ewp, dinv, nrm);

  // ---- input FCs (overwrite the transient pos/ewp region) ----
  fc_in_kernel<<<wgrid(NG), blk, 0, stream>>>(x_glom, W_in_g, b_in_g, lnig_s, lnig_b, xg0, NG);
  fc_in_kernel<<<wgrid(NC), blk, 0, stream>>>(x_cell, W_in_c, b_in_c, lnic_s, lnic_b, xc0, NC);

  // ---- two hetero MP layers (double-buffered) ----
  const int* rp_gg = S;
  const int* rp_cg = S + NG;
  const int* rp_cc = S + 2 * NG;
  float* xg_cur = xg0; float* xg_nxt = xg1;
  float* xc_cur = xc0; float* xc_nxt = xc1;
  for (int l = 0; l < 2; ++l) {
    const float* const* p = (const float* const*)(d_in + 14 + 10 * l);
    const float* W_gcn = p[0]; const float* b_gcn = p[1];
    const float* eps_cg = p[2]; const float* W_cg = p[3]; const float* b_cg = p[4];
    const float* eps_cc = p[5]; const float* W_cc = p[6]; const float* b_cc = p[7];
    const float* ln_s = p[8]; const float* ln_b = p[9];

    glom_layer_kernel<<<wgrid(NG), blk, 0, stream>>>(
        rp_gg, rp_cg, srcbuf, nrm, xg_cur, xc_cur, dinv,
        W_gcn, b_gcn, eps_cg, W_cg, b_cg, ln_s, ln_b, xg_nxt, NG);
    cell_layer_kernel<<<wgrid(NC), blk, 0, stream>>>(
        rp_cc, srcbuf, xc_cur, eps_cc, W_cc, b_cc, ln_s, ln_b, xc_nxt, NC);

    float* t;
    t = xg_cur; xg_cur = xg_nxt; xg_nxt = t;
    t = xc_cur; xc_cur = xc_nxt; xc_nxt = t;
  }

  out_kernel<<<wgrid(NG), blk, 0, stream>>>(xg_cur, W_outp, b_outp, (float*)d_out, NG);
}

// Round 5
// 1016.603 us; speedup vs baseline: 2.3355x; 1.0624x over previous
//
#include <hip/hip_runtime.h>
#include <hip/hip_fp16.h>

#define NG 50000
#define NC 100000
#define DIN 128
#define D 64
#define EGG 800000
#define ECG 1600000
#define ECC 1600000
#define LN_EPS 1e-5f

#define SCAN_N (2 * NG + NC)            // 200000 concatenated counters
#define SCAN_TPB 256
#define SCAN_PER_THREAD 8
#define SCAN_TILE (SCAN_TPB * SCAN_PER_THREAD)   // 2048
#define SCAN_NBLK ((SCAN_N + SCAN_TILE - 1) / SCAN_TILE)  // 98

__device__ __forceinline__ float wave_sum64(float v) {
#pragma unroll
  for (int off = 32; off > 0; off >>= 1) v += __shfl_xor(v, off);
  return v;
}

// Gather-accumulate over a CSR range from an fp16 feature table.
// Batched 64-wide index preload, 8-way unrolled MLP, weight-masked tail.
// acc += sum_e w_e * tab[src_e * 64 + lane]    (w_e = nrm[e] or 1.0)
__device__ __forceinline__ float csr_gather_h(
    const int* __restrict__ src, const float* __restrict__ nrm,
    const __half* __restrict__ tab, int e0, int e1, int lane) {
  float a0 = 0.f, a1 = 0.f, a2 = 0.f, a3 = 0.f;
  float a4 = 0.f, a5 = 0.f, a6 = 0.f, a7 = 0.f;
  for (int base = e0; base < e1; base += 64) {
    int cnt = e1 - base; if (cnt > 64) cnt = 64;
    int sidx = 0; float w = 0.0f;
    if (lane < cnt) {
      sidx = src[base + lane];
      w = nrm ? nrm[base + lane] : 1.0f;
    }
    int jend = (cnt + 7) & ~7;
    for (int j = 0; j < jend; j += 8) {
      int s0 = __shfl(sidx, j + 0), s1 = __shfl(sidx, j + 1);
      int s2 = __shfl(sidx, j + 2), s3 = __shfl(sidx, j + 3);
      int s4 = __shfl(sidx, j + 4), s5 = __shfl(sidx, j + 5);
      int s6 = __shfl(sidx, j + 6), s7 = __shfl(sidx, j + 7);
      float n0 = __shfl(w, j + 0), n1 = __shfl(w, j + 1);
      float n2 = __shfl(w, j + 2), n3 = __shfl(w, j + 3);
      float n4 = __shfl(w, j + 4), n5 = __shfl(w, j + 5);
      float n6 = __shfl(w, j + 6), n7 = __shfl(w, j + 7);
      a0 = fmaf(n0, __half2float(tab[(size_t)s0 * D + lane]), a0);
      a1 = fmaf(n1, __half2float(tab[(size_t)s1 * D + lane]), a1);
      a2 = fmaf(n2, __half2float(tab[(size_t)s2 * D + lane]), a2);
      a3 = fmaf(n3, __half2float(tab[(size_t)s3 * D + lane]), a3);
      a4 = fmaf(n4, __half2float(tab[(size_t)s4 * D + lane]), a4);
      a5 = fmaf(n5, __half2float(tab[(size_t)s5 * D + lane]), a5);
      a6 = fmaf(n6, __half2float(tab[(size_t)s6 * D + lane]), a6);
      a7 = fmaf(n7, __half2float(tab[(size_t)s7 * D + lane]), a7);
    }
  }
  return ((a0 + a1) + (a2 + a3)) + ((a4 + a5) + (a6 + a7));
}

// ---------------- dense input FC: y = relu(LN(x @ W + b)) -> fp16 ----------
__global__ __launch_bounds__(256) void fc_in_kernel(
    const float* __restrict__ x, const float* __restrict__ W,
    const float* __restrict__ b, const float* __restrict__ s,
    const float* __restrict__ beta, __half* __restrict__ y, int n) {
  int wid = (int)(((size_t)blockIdx.x * blockDim.x + threadIdx.x) >> 6);
  int lane = threadIdx.x & 63;
  if (wid >= n) return;
  const float* xr = x + (size_t)wid * DIN;
  float v0 = xr[lane];
  float v1 = xr[64 + lane];
  float acc = b[lane];
#pragma unroll
  for (int k = 0; k < 64; ++k)
    acc = fmaf(__shfl(v0, k), W[k * 64 + lane], acc);
#pragma unroll
  for (int k = 0; k < 64; ++k)
    acc = fmaf(__shfl(v1, k), W[(k + 64) * 64 + lane], acc);
  float m = wave_sum64(acc) * (1.0f / 64.0f);
  float d = acc - m;
  float var = wave_sum64(d * d) * (1.0f / 64.0f);
  float o = d * rsqrtf(var + LN_EPS) * s[lane] + beta[lane];
  y[(size_t)wid * D + lane] = __float2half(fmaxf(o, 0.0f));
}

// ---------------- CSR build: single atomic pass ----------------------------
__global__ __launch_bounds__(256) void passA_kernel(
    const int* __restrict__ ei_gg, const int* __restrict__ ei_cg,
    const int* __restrict__ ei_cc, int* __restrict__ cnt,
    int* __restrict__ pos_gg, int* __restrict__ pos_cg,
    int* __restrict__ pos_cc) {
  int e = blockIdx.x * 256 + threadIdx.x;
  if (e < EGG) pos_gg[e] = atomicAdd(&cnt[ei_gg[EGG + e]], 1);
  if (e < ECG) pos_cg[e] = atomicAdd(&cnt[NG + ei_cg[ECG + e]], 1);
  if (e < ECC) pos_cc[e] = atomicAdd(&cnt[2 * NG + ei_cc[ECC + e]], 1);
}

// ---------------- hierarchical exclusive scan over cnt[0..SCAN_N) ----------
__global__ __launch_bounds__(SCAN_TPB) void scan_blocksum_kernel(
    const int* __restrict__ cnt, int* __restrict__ bsum) {
  __shared__ int sh[SCAN_TPB / 64];
  int t = threadIdx.x;
  int base = blockIdx.x * SCAN_TILE + t * SCAN_PER_THREAD;
  int s = 0;
#pragma unroll
  for (int k = 0; k < SCAN_PER_THREAD; ++k) {
    int i = base + k;
    if (i < SCAN_N) s += cnt[i];
  }
#pragma unroll
  for (int off = 32; off > 0; off >>= 1) s += __shfl_xor(s, off);
  if ((t & 63) == 0) sh[t >> 6] = s;
  __syncthreads();
  if (t == 0) {
    int tot = 0;
#pragma unroll
    for (int w = 0; w < SCAN_TPB / 64; ++w) tot += sh[w];
    bsum[blockIdx.x] = tot;
  }
}

__global__ void scan_bsum_kernel(int* __restrict__ bsum, int* __restrict__ S) {
  if (threadIdx.x == 0) {
    int acc = 0;
    for (int b = 0; b < SCAN_NBLK; ++b) {
      int v = bsum[b]; bsum[b] = acc; acc += v;
    }
    S[SCAN_N] = acc;
  }
}

__global__ __launch_bounds__(SCAN_TPB) void scan_final_kernel(
    const int* __restrict__ cnt, const int* __restrict__ bsum,
    int* __restrict__ S) {
  int t = threadIdx.x;
  int lane = t & 63;
  int base = blockIdx.x * SCAN_TILE + t * SCAN_PER_THREAD;
  int v[SCAN_PER_THREAD];
  int s = 0;
#pragma unroll
  for (int k = 0; k < SCAN_PER_THREAD; ++k) {
    int i = base + k;
    v[k] = (i < SCAN_N) ? cnt[i] : 0;
    s += v[k];
  }
  int sc = s;
#pragma unroll
  for (int off = 1; off < 64; off <<= 1) {
    int u = __shfl_up(sc, off);
    if (lane >= off) sc += u;
  }
  __shared__ int wsum[SCAN_TPB / 64];
  if (lane == 63) wsum[t >> 6] = sc;
  __syncthreads();
  int wbase = 0;
  for (int w = 0; w < (t >> 6); ++w) wbase += wsum[w];
  int ex = bsum[blockIdx.x] + wbase + (sc - s);
#pragma unroll
  for (int k = 0; k < SCAN_PER_THREAD; ++k) {
    int i = base + k;
    if (i < SCAN_N) S[i] = ex;
    ex += v[k];
  }
}

// ---------------- atomic-free scatter into the unified src buffer ----------
__global__ __launch_bounds__(256) void scatter_kernel(
    const int* __restrict__ ei_gg, const float* __restrict__ ew_gg,
    const int* __restrict__ ei_cg, const int* __restrict__ ei_cc,
    const int* __restrict__ S, const int* __restrict__ pos_gg,
    const int* __restrict__ pos_cg, const int* __restrict__ pos_cc,
    int* __restrict__ srcbuf, float* __restrict__ ewp) {
  int e = blockIdx.x * 256 + threadIdx.x;
  if (e < EGG) {
    int d = ei_gg[EGG + e];
    int p = S[d] + pos_gg[e];
    srcbuf[p] = ei_gg[e];
    ewp[p] = ew_gg[e];
  }
  if (e < ECG) {
    int d = ei_cg[ECG + e];
    int p = S[NG + d] + pos_cg[e];
    srcbuf[p] = ei_cg[e];
  }
  if (e < ECC) {
    int d = ei_cc[ECC + e];
    int p = S[2 * NG + d] + pos_cc[e];
    srcbuf[p] = ei_cc[e];
  }
}

// dinv[i] = rsqrt(1 + segment sum of permuted edge weights)
__global__ __launch_bounds__(256) void deg_kernel(
    const int* __restrict__ S, const float* __restrict__ ewp,
    float* __restrict__ dinv) {
  int i = (int)(((size_t)blockIdx.x * blockDim.x + threadIdx.x) >> 6);
  int lane = threadIdx.x & 63;
  if (i >= NG) return;
  int e0 = S[i], e1 = S[i + 1];
  float s = 0.0f;
  for (int e = e0 + lane; e < e1; e += 64) s += ewp[e];
  s = wave_sum64(s);
  if (lane == 0) dinv[i] = rsqrtf(s + 1.0f);
}

// nrm[e] = dinv[src] * ew * dinv[dst]
__global__ __launch_bounds__(256) void nrm_kernel(
    const int* __restrict__ S, const int* __restrict__ srcbuf,
    const float* __restrict__ ewp, const float* __restrict__ dinv,
    float* __restrict__ nrm) {
  int i = (int)(((size_t)blockIdx.x * blockDim.x + threadIdx.x) >> 6);
  int lane = threadIdx.x & 63;
  if (i >= NG) return;
  float di = dinv[i];
  int e0 = S[i], e1 = S[i + 1];
  for (int e = e0 + lane; e < e1; e += 64)
    nrm[e] = dinv[srcbuf[e]] * ewp[e] * di;
}

// ---------------- fused glom layer -----------------------------------------
__global__ __launch_bounds__(256) void glom_layer_kernel(
    const int* __restrict__ rp_gg, const int* __restrict__ rp_cg,
    const int* __restrict__ srcbuf, const float* __restrict__ nrm_gg,
    const __half* __restrict__ xg_old, const __half* __restrict__ xc_old,
    const float* __restrict__ dinv,
    const float* __restrict__ W_gcn, const float* __restrict__ b_gcn,
    const float* __restrict__ eps_cg, const float* __restrict__ W_cg,
    const float* __restrict__ b_cg,
    const float* __restrict__ ls, const float* __restrict__ lb,
    __half* __restrict__ xg_new, int n) {
  int i = (int)(((size_t)blockIdx.x * blockDim.x + threadIdx.x) >> 6);
  int lane = threadIdx.x & 63;
  if (i >= n) return;
  float self = __half2float(xg_old[(size_t)i * D + lane]);
  float di = dinv[i];
  float accG = di * di * self
             + csr_gather_h(srcbuf, nrm_gg, xg_old, rp_gg[i], rp_gg[i + 1], lane);
  float accC = csr_gather_h(srcbuf, nullptr, xc_old, rp_cg[i], rp_cg[i + 1], lane);
  float gcn = b_gcn[lane];
#pragma unroll
  for (int k = 0; k < 64; ++k)
    gcn = fmaf(__shfl(accG, k), W_gcn[k * 64 + lane], gcn);
  float h = (1.0f + eps_cg[0]) * self + accC;
  float gin = b_cg[lane];
#pragma unroll
  for (int k = 0; k < 64; ++k)
    gin = fmaf(__shfl(h, k), W_cg[k * 64 + lane], gin);
  float g = gcn + fmaxf(gin, 0.0f);
  float m = wave_sum64(g) * (1.0f / 64.0f);
  float d = g - m;
  float var = wave_sum64(d * d) * (1.0f / 64.0f);
  float o = d * rsqrtf(var + LN_EPS) * ls[lane] + lb[lane];
  xg_new[(size_t)i * D + lane] = __float2half(fmaxf(o, 0.0f));
}

// ---------------- fused cell layer -----------------------------------------
__global__ __launch_bounds__(256) void cell_layer_kernel(
    const int* __restrict__ rp_cc, const int* __restrict__ srcbuf,
    const __half* __restrict__ xc_old,
    const float* __restrict__ eps_cc, const float* __restrict__ W_cc,
    const float* __restrict__ b_cc,
    const float* __restrict__ ls, const float* __restrict__ lb,
    __half* __restrict__ xc_new, int n) {
  int i = (int)(((size_t)blockIdx.x * blockDim.x + threadIdx.x) >> 6);
  int lane = threadIdx.x & 63;
  if (i >= n) return;
  float self = __half2float(xc_old[(size_t)i * D + lane]);
  float acc = csr_gather_h(srcbuf, nullptr, xc_old, rp_cc[i], rp_cc[i + 1], lane);
  float h = (1.0f + eps_cc[0]) * self + acc;
  float gin = b_cc[lane];
#pragma unroll
  for (int k = 0; k < 64; ++k)
    gin = fmaf(__shfl(h, k), W_cc[k * 64 + lane], gin);
  float g = fmaxf(gin, 0.0f);
  float m = wave_sum64(g) * (1.0f / 64.0f);
  float d = g - m;
  float var = wave_sum64(d * d) * (1.0f / 64.0f);
  float o = d * rsqrtf(var + LN_EPS) * ls[lane] + lb[lane];
  xc_new[(size_t)i * D + lane] = __float2half(fmaxf(o, 0.0f));
}

// ---------------- output head: wave per row --------------------------------
__global__ __launch_bounds__(256) void out_kernel(
    const __half* __restrict__ xg, const float* __restrict__ W,
    const float* __restrict__ b, float* __restrict__ out, int n) {
  int wid = (int)(((size_t)blockIdx.x * blockDim.x + threadIdx.x) >> 6);
  int lane = threadIdx.x & 63;
  if (wid >= n) return;
  float v = __half2float(xg[(size_t)wid * D + lane]);
  float a0 = wave_sum64(v * W[lane * 3 + 0]) + b[0];
  float a1 = wave_sum64(v * W[lane * 3 + 1]) + b[1];
  float a2 = wave_sum64(v * W[lane * 3 + 2]) + b[2];
  float m = fmaxf(a0, fmaxf(a1, a2));
  float e0 = expf(a0 - m), e1 = expf(a1 - m), e2 = expf(a2 - m);
  float inv = 1.0f / (e0 + e1 + e2);
  if (lane == 0) {
    out[(size_t)wid * 3 + 0] = e0 * inv;
    out[(size_t)wid * 3 + 1] = e1 * inv;
    out[(size_t)wid * 3 + 2] = e2 * inv;
  }
}

extern "C" void kernel_launch(void* const* d_in, const int* in_sizes, int n_in,
                              void* d_out, int out_size, void* d_ws, size_t ws_size,
                              hipStream_t stream) {
  const float* x_glom = (const float*)d_in[0];
  const float* x_cell = (const float*)d_in[1];
  const int*   ei_gg  = (const int*)d_in[2];
  const float* ew_gg  = (const float*)d_in[3];
  const int*   ei_cg  = (const int*)d_in[4];
  const int*   ei_cc  = (const int*)d_in[5];
  const float* W_in_g = (const float*)d_in[6];
  const float* b_in_g = (const float*)d_in[7];
  const float* lnig_s = (const float*)d_in[8];
  const float* lnig_b = (const float*)d_in[9];
  const float* W_in_c = (const float*)d_in[10];
  const float* b_in_c = (const float*)d_in[11];
  const float* lnic_s = (const float*)d_in[12];
  const float* lnic_b = (const float*)d_in[13];
  const float* W_outp = (const float*)d_in[34];
  const float* b_outp = (const float*)d_in[35];

  // ---- workspace layout (~60 MB) ----
  // fp16 feature tables, fp32 everything else.
  char* W0 = (char*)d_ws;
  __half* xg0 = (__half*)W0;                         W0 += (size_t)NG * D * 2;
  __half* xg1 = (__half*)W0;                         W0 += (size_t)NG * D * 2;
  __half* xc0 = (__half*)W0;                         W0 += (size_t)NC * D * 2;
  __half* xc1 = (__half*)W0;                         W0 += (size_t)NC * D * 2;
  float* dinv = (float*)W0;                          W0 += NG * 4;
  float* nrm  = (float*)W0;                          W0 += EGG * 4;
  int* cnt    = (int*)W0;                            W0 += SCAN_N * 4;
  int* S      = (int*)W0;                            W0 += (SCAN_N + 1) * 4;
  int* bsum   = (int*)W0;                            W0 += SCAN_NBLK * 4;
  int* srcbuf = (int*)W0;                            W0 += (size_t)(EGG + ECG + ECC) * 4;
  // transient region (dead before fc_in writes xc0/xc1): pos arrays + permuted ew
  // xc0+xc1 region = 25.6 MB >= 19.2 MB needed.
  int* pos_gg = (int*)xc0;
  int* pos_cg = pos_gg + EGG;
  int* pos_cc = pos_cg + ECG;
  float* ewp  = (float*)(pos_cc + ECC);

  dim3 blk(256);
  auto wgrid = [](long long waves) { return dim3((unsigned)((waves + 3) / 4)); };
  auto egrid = [](long long e) { return dim3((unsigned)((e + 255) / 256)); };

  // ---- CSR build: 1 atomic pass + hierarchical scan + atomic-free scatter --
  hipMemsetAsync(cnt, 0, SCAN_N * sizeof(int), stream);
  passA_kernel<<<egrid(ECG), blk, 0, stream>>>(
      ei_gg, ei_cg, ei_cc, cnt, pos_gg, pos_cg, pos_cc);
  scan_blocksum_kernel<<<dim3(SCAN_NBLK), dim3(SCAN_TPB), 0, stream>>>(cnt, bsum);
  scan_bsum_kernel<<<dim3(1), dim3(64), 0, stream>>>(bsum, S);
  scan_final_kernel<<<dim3(SCAN_NBLK), dim3(SCAN_TPB), 0, stream>>>(cnt, bsum, S);
  scatter_kernel<<<egrid(ECG), blk, 0, stream>>>(
      ei_gg, ew_gg, ei_cg, ei_cc, S, pos_gg, pos_cg, pos_cc, srcbuf, ewp);
  deg_kernel<<<wgrid(NG), blk, 0, stream>>>(S, ewp, dinv);
  nrm_kernel<<<wgrid(NG), blk, 0, stream>>>(S, srcbuf, ewp, dinv, nrm);

  // ---- input FCs (xc0 write overwrites the transient pos/ewp region) ----
  fc_in_kernel<<<wgrid(NG), blk, 0, stream>>>(x_glom, W_in_g, b_in_g, lnig_s, lnig_b, xg0, NG);
  fc_in_kernel<<<wgrid(NC), blk, 0, stream>>>(x_cell, W_in_c, b_in_c, lnic_s, lnic_b, xc0, NC);

  // ---- two hetero MP layers (double-buffered) ----
  const int* rp_gg = S;
  const int* rp_cg = S + NG;
  const int* rp_cc = S + 2 * NG;
  __half* xg_cur = xg0; __half* xg_nxt = xg1;
  __half* xc_cur = xc0; __half* xc_nxt = xc1;
  for (int l = 0; l < 2; ++l) {
    const float* const* p = (const float* const*)(d_in + 14 + 10 * l);
    const float* W_gcn = p[0]; const float* b_gcn = p[1];
    const float* eps_cg = p[2]; const float* W_cg = p[3]; const float* b_cg = p[4];
    const float* eps_cc = p[5]; const float* W_cc = p[6]; const float* b_cc = p[7];
    const float* ln_s = p[8]; const float* ln_b = p[9];

    glom_layer_kernel<<<wgrid(NG), blk, 0, stream>>>(
        rp_gg, rp_cg, srcbuf, nrm, xg_cur, xc_cur, dinv,
        W_gcn, b_gcn, eps_cg, W_cg, b_cg, ln_s, ln_b, xg_nxt, NG);
    cell_layer_kernel<<<wgrid(NC), blk, 0, stream>>>(
        rp_cc, srcbuf, xc_cur, eps_cc, W_cc, b_cc, ln_s, ln_b, xc_nxt, NC);

    __half* t;
    t = xg_cur; xg_cur = xg_nxt; xg_nxt = t;
    t = xc_cur; xc_cur = xc_nxt; xc_nxt = t;
  }

  out_kernel<<<wgrid(NG), blk, 0, stream>>>(xg_cur, W_outp, b_outp, (float*)d_out, NG);
}

// Round 6
// 948.207 us; speedup vs baseline: 2.5039x; 1.0721x over previous
//
#include <hip/hip_runtime.h>
#include <hip/hip_fp16.h>

#define NG 50000
#define NC 100000
#define DIN 128
#define D 64
#define EGG 800000
#define ECG 1600000
#define ECC 1600000
#define LN_EPS 1e-5f

#define SCAN_N (2 * NG + NC)            // 200000 concatenated counters
#define SCAN_TPB 256
#define SCAN_PER_THREAD 8
#define SCAN_TILE (SCAN_TPB * SCAN_PER_THREAD)   // 2048
#define SCAN_NBLK ((SCAN_N + SCAN_TILE - 1) / SCAN_TILE)  // 98

__device__ __forceinline__ float wave_sum64(float v) {
#pragma unroll
  for (int off = 32; off > 0; off >>= 1) v += __shfl_xor(v, off);
  return v;
}

// Gather-accumulate over a CSR range from an fp16 feature table.
// Pair-edge layout: lane = h*32+m (h = edge parity, m = dim pair). Each lane
// loads a half2 (dims 2m,2m+1) of edge j+2p+h -> one load instr covers 2 rows;
// 16-edge unroll keeps 16 rows in flight per wave. Tail edges are masked by
// w=0 (preload); they read row 0 harmlessly.
// Returns sum_e w_e * tab[src_e*64 + lane]  redistributed to lane=dim layout.
__device__ __forceinline__ float csr_gather_h2(
    const int* __restrict__ src, const float* __restrict__ nrm,
    const __half* __restrict__ tab, int e0, int e1, int lane) {
  int h = lane >> 5;
  int m = lane & 31;
  float ax0 = 0.f, ax1 = 0.f, ax2 = 0.f, ax3 = 0.f;
  float ax4 = 0.f, ax5 = 0.f, ax6 = 0.f, ax7 = 0.f;
  float ay0 = 0.f, ay1 = 0.f, ay2 = 0.f, ay3 = 0.f;
  float ay4 = 0.f, ay5 = 0.f, ay6 = 0.f, ay7 = 0.f;
  for (int base = e0; base < e1; base += 64) {
    int cnt = e1 - base; if (cnt > 64) cnt = 64;
    int sidx = 0; float w = 0.0f;
    if (lane < cnt) {
      sidx = src[base + lane];
      w = nrm ? nrm[base + lane] : 1.0f;
    }
    int jend = (cnt + 15) & ~15;
    for (int j = 0; j < jend; j += 16) {
      int s0 = __shfl(sidx, j + 0 + h),  s1 = __shfl(sidx, j + 2 + h);
      int s2 = __shfl(sidx, j + 4 + h),  s3 = __shfl(sidx, j + 6 + h);
      int s4 = __shfl(sidx, j + 8 + h),  s5 = __shfl(sidx, j + 10 + h);
      int s6 = __shfl(sidx, j + 12 + h), s7 = __shfl(sidx, j + 14 + h);
      __half2 v0 = *(const __half2*)(tab + (size_t)s0 * D + 2 * m);
      __half2 v1 = *(const __half2*)(tab + (size_t)s1 * D + 2 * m);
      __half2 v2 = *(const __half2*)(tab + (size_t)s2 * D + 2 * m);
      __half2 v3 = *(const __half2*)(tab + (size_t)s3 * D + 2 * m);
      __half2 v4 = *(const __half2*)(tab + (size_t)s4 * D + 2 * m);
      __half2 v5 = *(const __half2*)(tab + (size_t)s5 * D + 2 * m);
      __half2 v6 = *(const __half2*)(tab + (size_t)s6 * D + 2 * m);
      __half2 v7 = *(const __half2*)(tab + (size_t)s7 * D + 2 * m);
      float w0 = __shfl(w, j + 0 + h),  w1 = __shfl(w, j + 2 + h);
      float w2 = __shfl(w, j + 4 + h),  w3 = __shfl(w, j + 6 + h);
      float w4 = __shfl(w, j + 8 + h),  w5 = __shfl(w, j + 10 + h);
      float w6 = __shfl(w, j + 12 + h), w7 = __shfl(w, j + 14 + h);
      ax0 = fmaf(w0, __low2float(v0), ax0); ay0 = fmaf(w0, __high2float(v0), ay0);
      ax1 = fmaf(w1, __low2float(v1), ax1); ay1 = fmaf(w1, __high2float(v1), ay1);
      ax2 = fmaf(w2, __low2float(v2), ax2); ay2 = fmaf(w2, __high2float(v2), ay2);
      ax3 = fmaf(w3, __low2float(v3), ax3); ay3 = fmaf(w3, __high2float(v3), ay3);
      ax4 = fmaf(w4, __low2float(v4), ax4); ay4 = fmaf(w4, __high2float(v4), ay4);
      ax5 = fmaf(w5, __low2float(v5), ax5); ay5 = fmaf(w5, __high2float(v5), ay5);
      ax6 = fmaf(w6, __low2float(v6), ax6); ay6 = fmaf(w6, __high2float(v6), ay6);
      ax7 = fmaf(w7, __low2float(v7), ax7); ay7 = fmaf(w7, __high2float(v7), ay7);
    }
  }
  float sx = ((ax0 + ax1) + (ax2 + ax3)) + ((ax4 + ax5) + (ax6 + ax7));
  float sy = ((ay0 + ay1) + (ay2 + ay3)) + ((ay4 + ay5) + (ay6 + ay7));
  sx += __shfl_xor(sx, 32);   // combine even/odd edge halves
  sy += __shfl_xor(sy, 32);
  // redistribute pair layout -> lane=dim: lane d takes comp (d&1) of pair d>>1
  float ev = __shfl(sx, lane >> 1);
  float od = __shfl(sy, lane >> 1);
  return (lane & 1) ? od : ev;
}

// ---------------- dense input FC: y = relu(LN(x @ W + b)) -> fp16 ----------
__global__ __launch_bounds__(256) void fc_in_kernel(
    const float* __restrict__ x, const float* __restrict__ W,
    const float* __restrict__ b, const float* __restrict__ s,
    const float* __restrict__ beta, __half* __restrict__ y, int n) {
  int wid = (int)(((size_t)blockIdx.x * blockDim.x + threadIdx.x) >> 6);
  int lane = threadIdx.x & 63;
  if (wid >= n) return;
  const float* xr = x + (size_t)wid * DIN;
  float v0 = xr[lane];
  float v1 = xr[64 + lane];
  float acc = b[lane];
#pragma unroll
  for (int k = 0; k < 64; ++k)
    acc = fmaf(__shfl(v0, k), W[k * 64 + lane], acc);
#pragma unroll
  for (int k = 0; k < 64; ++k)
    acc = fmaf(__shfl(v1, k), W[(k + 64) * 64 + lane], acc);
  float m = wave_sum64(acc) * (1.0f / 64.0f);
  float d = acc - m;
  float var = wave_sum64(d * d) * (1.0f / 64.0f);
  float o = d * rsqrtf(var + LN_EPS) * s[lane] + beta[lane];
  y[(size_t)wid * D + lane] = __float2half(fmaxf(o, 0.0f));
}

// ---------------- CSR build: single atomic pass ----------------------------
__global__ __launch_bounds__(256) void passA_kernel(
    const int* __restrict__ ei_gg, const int* __restrict__ ei_cg,
    const int* __restrict__ ei_cc, int* __restrict__ cnt,
    int* __restrict__ pos_gg, int* __restrict__ pos_cg,
    int* __restrict__ pos_cc) {
  int e = blockIdx.x * 256 + threadIdx.x;
  if (e < EGG) pos_gg[e] = atomicAdd(&cnt[ei_gg[EGG + e]], 1);
  if (e < ECG) pos_cg[e] = atomicAdd(&cnt[NG + ei_cg[ECG + e]], 1);
  if (e < ECC) pos_cc[e] = atomicAdd(&cnt[2 * NG + ei_cc[ECC + e]], 1);
}

// ---------------- hierarchical exclusive scan over cnt[0..SCAN_N) ----------
__global__ __launch_bounds__(SCAN_TPB) void scan_blocksum_kernel(
    const int* __restrict__ cnt, int* __restrict__ bsum) {
  __shared__ int sh[SCAN_TPB / 64];
  int t = threadIdx.x;
  int base = blockIdx.x * SCAN_TILE + t * SCAN_PER_THREAD;
  int s = 0;
#pragma unroll
  for (int k = 0; k < SCAN_PER_THREAD; ++k) {
    int i = base + k;
    if (i < SCAN_N) s += cnt[i];
  }
#pragma unroll
  for (int off = 32; off > 0; off >>= 1) s += __shfl_xor(s, off);
  if ((t & 63) == 0) sh[t >> 6] = s;
  __syncthreads();
  if (t == 0) {
    int tot = 0;
#pragma unroll
    for (int w = 0; w < SCAN_TPB / 64; ++w) tot += sh[w];
    bsum[blockIdx.x] = tot;
  }
}

__global__ void scan_bsum_kernel(int* __restrict__ bsum, int* __restrict__ S) {
  if (threadIdx.x == 0) {
    int acc = 0;
    for (int b = 0; b < SCAN_NBLK; ++b) {
      int v = bsum[b]; bsum[b] = acc; acc += v;
    }
    S[SCAN_N] = acc;
  }
}

__global__ __launch_bounds__(SCAN_TPB) void scan_final_kernel(
    const int* __restrict__ cnt, const int* __restrict__ bsum,
    int* __restrict__ S) {
  int t = threadIdx.x;
  int lane = t & 63;
  int base = blockIdx.x * SCAN_TILE + t * SCAN_PER_THREAD;
  int v[SCAN_PER_THREAD];
  int s = 0;
#pragma unroll
  for (int k = 0; k < SCAN_PER_THREAD; ++k) {
    int i = base + k;
    v[k] = (i < SCAN_N) ? cnt[i] : 0;
    s += v[k];
  }
  int sc = s;
#pragma unroll
  for (int off = 1; off < 64; off <<= 1) {
    int u = __shfl_up(sc, off);
    if (lane >= off) sc += u;
  }
  __shared__ int wsum[SCAN_TPB / 64];
  if (lane == 63) wsum[t >> 6] = sc;
  __syncthreads();
  int wbase = 0;
  for (int w = 0; w < (t >> 6); ++w) wbase += wsum[w];
  int ex = bsum[blockIdx.x] + wbase + (sc - s);
#pragma unroll
  for (int k = 0; k < SCAN_PER_THREAD; ++k) {
    int i = base + k;
    if (i < SCAN_N) S[i] = ex;
    ex += v[k];
  }
}

// ---------------- atomic-free scatter into the unified src buffer ----------
__global__ __launch_bounds__(256) void scatter_kernel(
    const int* __restrict__ ei_gg, const float* __restrict__ ew_gg,
    const int* __restrict__ ei_cg, const int* __restrict__ ei_cc,
    const int* __restrict__ S, const int* __restrict__ pos_gg,
    const int* __restrict__ pos_cg, const int* __restrict__ pos_cc,
    int* __restrict__ srcbuf, float* __restrict__ ewp) {
  int e = blockIdx.x * 256 + threadIdx.x;
  if (e < EGG) {
    int d = ei_gg[EGG + e];
    int p = S[d] + pos_gg[e];
    srcbuf[p] = ei_gg[e];
    ewp[p] = ew_gg[e];
  }
  if (e < ECG) {
    int d = ei_cg[ECG + e];
    int p = S[NG + d] + pos_cg[e];
    srcbuf[p] = ei_cg[e];
  }
  if (e < ECC) {
    int d = ei_cc[ECC + e];
    int p = S[2 * NG + d] + pos_cc[e];
    srcbuf[p] = ei_cc[e];
  }
}

// dinv[i] = rsqrt(1 + segment sum of permuted edge weights)
__global__ __launch_bounds__(256) void deg_kernel(
    const int* __restrict__ S, const float* __restrict__ ewp,
    float* __restrict__ dinv) {
  int i = (int)(((size_t)blockIdx.x * blockDim.x + threadIdx.x) >> 6);
  int lane = threadIdx.x & 63;
  if (i >= NG) return;
  int e0 = S[i], e1 = S[i + 1];
  float s = 0.0f;
  for (int e = e0 + lane; e < e1; e += 64) s += ewp[e];
  s = wave_sum64(s);
  if (lane == 0) dinv[i] = rsqrtf(s + 1.0f);
}

// nrm[e] = dinv[src] * ew * dinv[dst]
__global__ __launch_bounds__(256) void nrm_kernel(
    const int* __restrict__ S, const int* __restrict__ srcbuf,
    const float* __restrict__ ewp, const float* __restrict__ dinv,
    float* __restrict__ nrm) {
  int i = (int)(((size_t)blockIdx.x * blockDim.x + threadIdx.x) >> 6);
  int lane = threadIdx.x & 63;
  if (i >= NG) return;
  float di = dinv[i];
  int e0 = S[i], e1 = S[i + 1];
  for (int e = e0 + lane; e < e1; e += 64)
    nrm[e] = dinv[srcbuf[e]] * ewp[e] * di;
}

// ---------------- fused glom layer -----------------------------------------
__global__ __launch_bounds__(256) void glom_layer_kernel(
    const int* __restrict__ rp_gg, const int* __restrict__ rp_cg,
    const int* __restrict__ srcbuf, const float* __restrict__ nrm_gg,
    const __half* __restrict__ xg_old, const __half* __restrict__ xc_old,
    const float* __restrict__ dinv,
    const float* __restrict__ W_gcn, const float* __restrict__ b_gcn,
    const float* __restrict__ eps_cg, const float* __restrict__ W_cg,
    const float* __restrict__ b_cg,
    const float* __restrict__ ls, const float* __restrict__ lb,
    __half* __restrict__ xg_new, int n) {
  int i = (int)(((size_t)blockIdx.x * blockDim.x + threadIdx.x) >> 6);
  int lane = threadIdx.x & 63;
  if (i >= n) return;
  float self = __half2float(xg_old[(size_t)i * D + lane]);
  float di = dinv[i];
  float accG = di * di * self
             + csr_gather_h2(srcbuf, nrm_gg, xg_old, rp_gg[i], rp_gg[i + 1], lane);
  float accC = csr_gather_h2(srcbuf, nullptr, xc_old, rp_cg[i], rp_cg[i + 1], lane);
  float gcn = b_gcn[lane];
#pragma unroll
  for (int k = 0; k < 64; ++k)
    gcn = fmaf(__shfl(accG, k), W_gcn[k * 64 + lane], gcn);
  float h = (1.0f + eps_cg[0]) * self + accC;
  float gin = b_cg[lane];
#pragma unroll
  for (int k = 0; k < 64; ++k)
    gin = fmaf(__shfl(h, k), W_cg[k * 64 + lane], gin);
  float g = gcn + fmaxf(gin, 0.0f);
  float m = wave_sum64(g) * (1.0f / 64.0f);
  float d = g - m;
  float var = wave_sum64(d * d) * (1.0f / 64.0f);
  float o = d * rsqrtf(var + LN_EPS) * ls[lane] + lb[lane];
  xg_new[(size_t)i * D + lane] = __float2half(fmaxf(o, 0.0f));
}

// ---------------- fused cell layer -----------------------------------------
__global__ __launch_bounds__(256) void cell_layer_kernel(
    const int* __restrict__ rp_cc, const int* __restrict__ srcbuf,
    const __half* __restrict__ xc_old,
    const float* __restrict__ eps_cc, const float* __restrict__ W_cc,
    const float* __restrict__ b_cc,
    const float* __restrict__ ls, const float* __restrict__ lb,
    __half* __restrict__ xc_new, int n) {
  int i = (int)(((size_t)blockIdx.x * blockDim.x + threadIdx.x) >> 6);
  int lane = threadIdx.x & 63;
  if (i >= n) return;
  float self = __half2float(xc_old[(size_t)i * D + lane]);
  float acc = csr_gather_h2(srcbuf, nullptr, xc_old, rp_cc[i], rp_cc[i + 1], lane);
  float h = (1.0f + eps_cc[0]) * self + acc;
  float gin = b_cc[lane];
#pragma unroll
  for (int k = 0; k < 64; ++k)
    gin = fmaf(__shfl(h, k), W_cc[k * 64 + lane], gin);
  float g = fmaxf(gin, 0.0f);
  float m = wave_sum64(g) * (1.0f / 64.0f);
  float d = g - m;
  float var = wave_sum64(d * d) * (1.0f / 64.0f);
  float o = d * rsqrtf(var + LN_EPS) * ls[lane] + lb[lane];
  xc_new[(size_t)i * D + lane] = __float2half(fmaxf(o, 0.0f));
}

// ---------------- output head: wave per row --------------------------------
__global__ __launch_bounds__(256) void out_kernel(
    const __half* __restrict__ xg, const float* __restrict__ W,
    const float* __restrict__ b, float* __restrict__ out, int n) {
  int wid = (int)(((size_t)blockIdx.x * blockDim.x + threadIdx.x) >> 6);
  int lane = threadIdx.x & 63;
  if (wid >= n) return;
  float v = __half2float(xg[(size_t)wid * D + lane]);
  float a0 = wave_sum64(v * W[lane * 3 + 0]) + b[0];
  float a1 = wave_sum64(v * W[lane * 3 + 1]) + b[1];
  float a2 = wave_sum64(v * W[lane * 3 + 2]) + b[2];
  float m = fmaxf(a0, fmaxf(a1, a2));
  float e0 = expf(a0 - m), e1 = expf(a1 - m), e2 = expf(a2 - m);
  float inv = 1.0f / (e0 + e1 + e2);
  if (lane == 0) {
    out[(size_t)wid * 3 + 0] = e0 * inv;
    out[(size_t)wid * 3 + 1] = e1 * inv;
    out[(size_t)wid * 3 + 2] = e2 * inv;
  }
}

extern "C" void kernel_launch(void* const* d_in, const int* in_sizes, int n_in,
                              void* d_out, int out_size, void* d_ws, size_t ws_size,
                              hipStream_t stream) {
  const float* x_glom = (const float*)d_in[0];
  const float* x_cell = (const float*)d_in[1];
  const int*   ei_gg  = (const int*)d_in[2];
  const float* ew_gg  = (const float*)d_in[3];
  const int*   ei_cg  = (const int*)d_in[4];
  const int*   ei_cc  = (const int*)d_in[5];
  const float* W_in_g = (const float*)d_in[6];
  const float* b_in_g = (const float*)d_in[7];
  const float* lnig_s = (const float*)d_in[8];
  const float* lnig_b = (const float*)d_in[9];
  const float* W_in_c = (const float*)d_in[10];
  const float* b_in_c = (const float*)d_in[11];
  const float* lnic_s = (const float*)d_in[12];
  const float* lnic_b = (const float*)d_in[13];
  const float* W_outp = (const float*)d_in[34];
  const float* b_outp = (const float*)d_in[35];

  // ---- workspace layout (~60 MB) ----
  char* W0 = (char*)d_ws;
  __half* xg0 = (__half*)W0;                         W0 += (size_t)NG * D * 2;
  __half* xg1 = (__half*)W0;                         W0 += (size_t)NG * D * 2;
  __half* xc0 = (__half*)W0;                         W0 += (size_t)NC * D * 2;
  __half* xc1 = (__half*)W0;                         W0 += (size_t)NC * D * 2;
  float* dinv = (float*)W0;                          W0 += NG * 4;
  float* nrm  = (float*)W0;                          W0 += EGG * 4;
  int* cnt    = (int*)W0;                            W0 += SCAN_N * 4;
  int* S      = (int*)W0;                            W0 += (SCAN_N + 1) * 4;
  int* bsum   = (int*)W0;                            W0 += SCAN_NBLK * 4;
  int* srcbuf = (int*)W0;                            W0 += (size_t)(EGG + ECG + ECC) * 4;
  // transient region (dead before fc_in writes xc0/xc1): pos arrays + permuted ew
  int* pos_gg = (int*)xc0;
  int* pos_cg = pos_gg + EGG;
  int* pos_cc = pos_cg + ECG;
  float* ewp  = (float*)(pos_cc + ECC);

  dim3 blk(256);
  auto wgrid = [](long long waves) { return dim3((unsigned)((waves + 3) / 4)); };
  auto egrid = [](long long e) { return dim3((unsigned)((e + 255) / 256)); };

  // ---- CSR build: 1 atomic pass + hierarchical scan + atomic-free scatter --
  hipMemsetAsync(cnt, 0, SCAN_N * sizeof(int), stream);
  passA_kernel<<<egrid(ECG), blk, 0, stream>>>(
      ei_gg, ei_cg, ei_cc, cnt, pos_gg, pos_cg, pos_cc);
  scan_blocksum_kernel<<<dim3(SCAN_NBLK), dim3(SCAN_TPB), 0, stream>>>(cnt, bsum);
  scan_bsum_kernel<<<dim3(1), dim3(64), 0, stream>>>(bsum, S);
  scan_final_kernel<<<dim3(SCAN_NBLK), dim3(SCAN_TPB), 0, stream>>>(cnt, bsum, S);
  scatter_kernel<<<egrid(ECG), blk, 0, stream>>>(
      ei_gg, ew_gg, ei_cg, ei_cc, S, pos_gg, pos_cg, pos_cc, srcbuf, ewp);
  deg_kernel<<<wgrid(NG), blk, 0, stream>>>(S, ewp, dinv);
  nrm_kernel<<<wgrid(NG), blk, 0, stream>>>(S, srcbuf, ewp, dinv, nrm);

  // ---- input FCs (xc0 write overwrites the transient pos/ewp region) ----
  fc_in_kernel<<<wgrid(NG), blk, 0, stream>>>(x_glom, W_in_g, b_in_g, lnig_s, lnig_b, xg0, NG);
  fc_in_kernel<<<wgrid(NC), blk, 0, stream>>>(x_cell, W_in_c, b_in_c, lnic_s, lnic_b, xc0, NC);

  // ---- two hetero MP layers (double-buffered) ----
  const int* rp_gg = S;
  const int* rp_cg = S + NG;
  const int* rp_cc = S + 2 * NG;
  __half* xg_cur = xg0; __half* xg_nxt = xg1;
  __half* xc_cur = xc0; __half* xc_nxt = xc1;
  for (int l = 0; l < 2; ++l) {
    const float* const* p = (const float* const*)(d_in + 14 + 10 * l);
    const float* W_gcn = p[0]; const float* b_gcn = p[1];
    const float* eps_cg = p[2]; const float* W_cg = p[3]; const float* b_cg = p[4];
    const float* eps_cc = p[5]; const float* W_cc = p[6]; const float* b_cc = p[7];
    const float* ln_s = p[8]; const float* ln_b = p[9];

    glom_layer_kernel<<<wgrid(NG), blk, 0, stream>>>(
        rp_gg, rp_cg, srcbuf, nrm, xg_cur, xc_cur, dinv,
        W_gcn, b_gcn, eps_cg, W_cg, b_cg, ln_s, ln_b, xg_nxt, NG);
    cell_layer_kernel<<<wgrid(NC), blk, 0, stream>>>(
        rp_cc, srcbuf, xc_cur, eps_cc, W_cc, b_cc, ln_s, ln_b, xc_nxt, NC);

    __half* t;
    t = xg_cur; xg_cur = xg_nxt; xg_nxt = t;
    t = xc_cur; xc_cur = xc_nxt; xc_nxt = t;
  }

  out_kernel<<<wgrid(NG), blk, 0, stream>>>(xg_cur, W_outp, b_outp, (float*)d_out, NG);
}

// Round 7
// 941.828 us; speedup vs baseline: 2.5209x; 1.0068x over previous
//
#include <hip/hip_runtime.h>
#include <hip/hip_fp16.h>

#define NG 50000
#define NC 100000
#define DIN 128
#define D 64
#define EGG 800000
#define ECG 1600000
#define ECC 1600000
#define LN_EPS 1e-5f

#define SCAN_N (2 * NG + NC)            // 200000 concatenated counters
#define SCAN_TPB 256
#define SCAN_PER_THREAD 8
#define SCAN_TILE (SCAN_TPB * SCAN_PER_THREAD)   // 2048
#define SCAN_NBLK ((SCAN_N + SCAN_TILE - 1) / SCAN_TILE)  // 98

__device__ __forceinline__ float wave_sum64(float v) {
#pragma unroll
  for (int off = 32; off > 0; off >>= 1) v += __shfl_xor(v, off);
  return v;
}

// ---- pipelined fp16 CSR gather -------------------------------------------
// Pair-edge layout: lane = h*32+m (h = edge parity, m = dim pair). One half2
// load covers 2 dims of 1 of 2 edges; a 16-edge group = 8 loads/lane.
// Depth-2 pipeline: group j+16 is issued before group j is consumed ->
// 16 outstanding loads/wave in steady state. First-chunk indices/weights can
// be preloaded by the caller (pidx/pw) so the index miss overlaps earlier work.

__device__ __forceinline__ void gather_issue(
    const __half* __restrict__ tab, int sidx, int h, int m, int j,
    __half2* g) {
#pragma unroll
  for (int p = 0; p < 8; ++p) {
    int s = __shfl(sidx, j + 2 * p + h);
    g[p] = *(const __half2*)(tab + (size_t)s * D + 2 * m);
  }
}

__device__ __forceinline__ void gather_consume(
    float w, int h, int j, const __half2* g, float* ax, float* ay) {
#pragma unroll
  for (int p = 0; p < 8; ++p) {
    float wp = __shfl(w, j + 2 * p + h);
    ax[p] = fmaf(wp, __low2float(g[p]), ax[p]);
    ay[p] = fmaf(wp, __high2float(g[p]), ay[p]);
  }
}

// Returns sum_e w_e * tab[src_e*64 + lane] (lane = dim layout).
// pidx/pw: preloaded index/weight for element e0+lane (w=0 for masked lanes).
__device__ __forceinline__ float csr_gather_h2(
    const int* __restrict__ src, const float* __restrict__ nrm,
    const __half* __restrict__ tab, int e0, int e1, int lane,
    int pidx, float pw) {
  int h = lane >> 5;
  int m = lane & 31;
  float ax[8], ay[8];
#pragma unroll
  for (int p = 0; p < 8; ++p) { ax[p] = 0.0f; ay[p] = 0.0f; }
  bool first = true;
  for (int base = e0; base < e1; base += 64) {
    int cnt = e1 - base; if (cnt > 64) cnt = 64;
    int sidx; float w;
    if (first) {
      sidx = pidx; w = pw;
    } else {
      sidx = 0; w = 0.0f;
      if (lane < cnt) {
        sidx = src[base + lane];
        w = nrm ? nrm[base + lane] : 1.0f;
      }
    }
    first = false;
    int jend = (cnt + 15) & ~15;
    __half2 v[8], u[8];
    gather_issue(tab, sidx, h, m, 0, v);
    int j = 0;
    while (true) {
      if (j + 16 < jend) gather_issue(tab, sidx, h, m, j + 16, u);
      gather_consume(w, h, j, v, ax, ay);
      j += 16;
      if (j >= jend) break;
      if (j + 16 < jend) gather_issue(tab, sidx, h, m, j + 16, v);
      gather_consume(w, h, j, u, ax, ay);
      j += 16;
      if (j >= jend) break;
    }
  }
  float sx = ((ax[0] + ax[1]) + (ax[2] + ax[3])) + ((ax[4] + ax[5]) + (ax[6] + ax[7]));
  float sy = ((ay[0] + ay[1]) + (ay[2] + ay[3])) + ((ay[4] + ay[5]) + (ay[6] + ay[7]));
  sx += __shfl_xor(sx, 32);   // combine even/odd edge halves
  sy += __shfl_xor(sy, 32);
  // redistribute pair layout -> lane=dim: lane d takes comp (d&1) of pair d>>1
  float ev = __shfl(sx, lane >> 1);
  float od = __shfl(sy, lane >> 1);
  return (lane & 1) ? od : ev;
}

// ---------------- dense input FC: y = relu(LN(x @ W + b)) -> fp16 ----------
__global__ __launch_bounds__(256) void fc_in_kernel(
    const float* __restrict__ x, const float* __restrict__ W,
    const float* __restrict__ b, const float* __restrict__ s,
    const float* __restrict__ beta, __half* __restrict__ y, int n) {
  int wid = (int)(((size_t)blockIdx.x * blockDim.x + threadIdx.x) >> 6);
  int lane = threadIdx.x & 63;
  if (wid >= n) return;
  const float* xr = x + (size_t)wid * DIN;
  float v0 = xr[lane];
  float v1 = xr[64 + lane];
  float acc = b[lane];
#pragma unroll
  for (int k = 0; k < 64; ++k)
    acc = fmaf(__shfl(v0, k), W[k * 64 + lane], acc);
#pragma unroll
  for (int k = 0; k < 64; ++k)
    acc = fmaf(__shfl(v1, k), W[(k + 64) * 64 + lane], acc);
  float m = wave_sum64(acc) * (1.0f / 64.0f);
  float d = acc - m;
  float var = wave_sum64(d * d) * (1.0f / 64.0f);
  float o = d * rsqrtf(var + LN_EPS) * s[lane] + beta[lane];
  y[(size_t)wid * D + lane] = __float2half(fmaxf(o, 0.0f));
}

// ---------------- CSR build: single atomic pass ----------------------------
__global__ __launch_bounds__(256) void passA_kernel(
    const int* __restrict__ ei_gg, const int* __restrict__ ei_cg,
    const int* __restrict__ ei_cc, int* __restrict__ cnt,
    int* __restrict__ pos_gg, int* __restrict__ pos_cg,
    int* __restrict__ pos_cc) {
  int e = blockIdx.x * 256 + threadIdx.x;
  if (e < EGG) pos_gg[e] = atomicAdd(&cnt[ei_gg[EGG + e]], 1);
  if (e < ECG) pos_cg[e] = atomicAdd(&cnt[NG + ei_cg[ECG + e]], 1);
  if (e < ECC) pos_cc[e] = atomicAdd(&cnt[2 * NG + ei_cc[ECC + e]], 1);
}

// ---------------- hierarchical exclusive scan over cnt[0..SCAN_N) ----------
__global__ __launch_bounds__(SCAN_TPB) void scan_blocksum_kernel(
    const int* __restrict__ cnt, int* __restrict__ bsum) {
  __shared__ int sh[SCAN_TPB / 64];
  int t = threadIdx.x;
  int base = blockIdx.x * SCAN_TILE + t * SCAN_PER_THREAD;
  int s = 0;
#pragma unroll
  for (int k = 0; k < SCAN_PER_THREAD; ++k) {
    int i = base + k;
    if (i < SCAN_N) s += cnt[i];
  }
#pragma unroll
  for (int off = 32; off > 0; off >>= 1) s += __shfl_xor(s, off);
  if ((t & 63) == 0) sh[t >> 6] = s;
  __syncthreads();
  if (t == 0) {
    int tot = 0;
#pragma unroll
    for (int w = 0; w < SCAN_TPB / 64; ++w) tot += sh[w];
    bsum[blockIdx.x] = tot;
  }
}

__global__ void scan_bsum_kernel(int* __restrict__ bsum, int* __restrict__ S) {
  if (threadIdx.x == 0) {
    int acc = 0;
    for (int b = 0; b < SCAN_NBLK; ++b) {
      int v = bsum[b]; bsum[b] = acc; acc += v;
    }
    S[SCAN_N] = acc;
  }
}

__global__ __launch_bounds__(SCAN_TPB) void scan_final_kernel(
    const int* __restrict__ cnt, const int* __restrict__ bsum,
    int* __restrict__ S) {
  int t = threadIdx.x;
  int lane = t & 63;
  int base = blockIdx.x * SCAN_TILE + t * SCAN_PER_THREAD;
  int v[SCAN_PER_THREAD];
  int s = 0;
#pragma unroll
  for (int k = 0; k < SCAN_PER_THREAD; ++k) {
    int i = base + k;
    v[k] = (i < SCAN_N) ? cnt[i] : 0;
    s += v[k];
  }
  int sc = s;
#pragma unroll
  for (int off = 1; off < 64; off <<= 1) {
    int u = __shfl_up(sc, off);
    if (lane >= off) sc += u;
  }
  __shared__ int wsum[SCAN_TPB / 64];
  if (lane == 63) wsum[t >> 6] = sc;
  __syncthreads();
  int wbase = 0;
  for (int w = 0; w < (t >> 6); ++w) wbase += wsum[w];
  int ex = bsum[blockIdx.x] + wbase + (sc - s);
#pragma unroll
  for (int k = 0; k < SCAN_PER_THREAD; ++k) {
    int i = base + k;
    if (i < SCAN_N) S[i] = ex;
    ex += v[k];
  }
}

// ---------------- atomic-free scatter into the unified src buffer ----------
__global__ __launch_bounds__(256) void scatter_kernel(
    const int* __restrict__ ei_gg, const float* __restrict__ ew_gg,
    const int* __restrict__ ei_cg, const int* __restrict__ ei_cc,
    const int* __restrict__ S, const int* __restrict__ pos_gg,
    const int* __restrict__ pos_cg, const int* __restrict__ pos_cc,
    int* __restrict__ srcbuf, float* __restrict__ ewp) {
  int e = blockIdx.x * 256 + threadIdx.x;
  if (e < EGG) {
    int d = ei_gg[EGG + e];
    int p = S[d] + pos_gg[e];
    srcbuf[p] = ei_gg[e];
    ewp[p] = ew_gg[e];
  }
  if (e < ECG) {
    int d = ei_cg[ECG + e];
    int p = S[NG + d] + pos_cg[e];
    srcbuf[p] = ei_cg[e];
  }
  if (e < ECC) {
    int d = ei_cc[ECC + e];
    int p = S[2 * NG + d] + pos_cc[e];
    srcbuf[p] = ei_cc[e];
  }
}

// dinv[i] = rsqrt(1 + segment sum of permuted edge weights)
__global__ __launch_bounds__(256) void deg_kernel(
    const int* __restrict__ S, const float* __restrict__ ewp,
    float* __restrict__ dinv) {
  int i = (int)(((size_t)blockIdx.x * blockDim.x + threadIdx.x) >> 6);
  int lane = threadIdx.x & 63;
  if (i >= NG) return;
  int e0 = S[i], e1 = S[i + 1];
  float s = 0.0f;
  for (int e = e0 + lane; e < e1; e += 64) s += ewp[e];
  s = wave_sum64(s);
  if (lane == 0) dinv[i] = rsqrtf(s + 1.0f);
}

// nrm[e] = dinv[src] * ew * dinv[dst]
__global__ __launch_bounds__(256) void nrm_kernel(
    const int* __restrict__ S, const int* __restrict__ srcbuf,
    const float* __restrict__ ewp, const float* __restrict__ dinv,
    float* __restrict__ nrm) {
  int i = (int)(((size_t)blockIdx.x * blockDim.x + threadIdx.x) >> 6);
  int lane = threadIdx.x & 63;
  if (i >= NG) return;
  float di = dinv[i];
  int e0 = S[i], e1 = S[i + 1];
  for (int e = e0 + lane; e < e1; e += 64)
    nrm[e] = dinv[srcbuf[e]] * ewp[e] * di;
}

// ---------------- fused glom layer -----------------------------------------
__global__ __launch_bounds__(256) void glom_layer_kernel(
    const int* __restrict__ rp_gg, const int* __restrict__ rp_cg,
    const int* __restrict__ srcbuf, const float* __restrict__ nrm_gg,
    const __half* __restrict__ xg_old, const __half* __restrict__ xc_old,
    const float* __restrict__ dinv,
    const float* __restrict__ W_gcn, const float* __restrict__ b_gcn,
    const float* __restrict__ eps_cg, const float* __restrict__ W_cg,
    const float* __restrict__ b_cg,
    const float* __restrict__ ls, const float* __restrict__ lb,
    __half* __restrict__ xg_new, int n) {
  int i = (int)(((size_t)blockIdx.x * blockDim.x + threadIdx.x) >> 6);
  int lane = threadIdx.x & 63;
  if (i >= n) return;
  int ge0 = rp_gg[i], ge1 = rp_gg[i + 1];
  int fe0 = rp_cg[i], fe1 = rp_cg[i + 1];
  // hoist first-chunk index/weight loads for BOTH gathers off the chain
  int gidx = 0; float gw = 0.0f;
  if (ge0 + lane < ge1) { gidx = srcbuf[ge0 + lane]; gw = nrm_gg[ge0 + lane]; }
  int cidx = 0; float cw = 0.0f;
  if (fe0 + lane < fe1) { cidx = srcbuf[fe0 + lane]; cw = 1.0f; }
  float self = __half2float(xg_old[(size_t)i * D + lane]);
  float di = dinv[i];
  float accG = di * di * self
             + csr_gather_h2(srcbuf, nrm_gg, xg_old, ge0, ge1, lane, gidx, gw);
  float accC = csr_gather_h2(srcbuf, nullptr, xc_old, fe0, fe1, lane, cidx, cw);
  float gcn = b_gcn[lane];
#pragma unroll
  for (int k = 0; k < 64; ++k)
    gcn = fmaf(__shfl(accG, k), W_gcn[k * 64 + lane], gcn);
  float h = (1.0f + eps_cg[0]) * self + accC;
  float gin = b_cg[lane];
#pragma unroll
  for (int k = 0; k < 64; ++k)
    gin = fmaf(__shfl(h, k), W_cg[k * 64 + lane], gin);
  float g = gcn + fmaxf(gin, 0.0f);
  float m = wave_sum64(g) * (1.0f / 64.0f);
  float d = g - m;
  float var = wave_sum64(d * d) * (1.0f / 64.0f);
  float o = d * rsqrtf(var + LN_EPS) * ls[lane] + lb[lane];
  xg_new[(size_t)i * D + lane] = __float2half(fmaxf(o, 0.0f));
}

// ---------------- fused cell layer -----------------------------------------
__global__ __launch_bounds__(256) void cell_layer_kernel(
    const int* __restrict__ rp_cc, const int* __restrict__ srcbuf,
    const __half* __restrict__ xc_old,
    const float* __restrict__ eps_cc, const float* __restrict__ W_cc,
    const float* __restrict__ b_cc,
    const float* __restrict__ ls, const float* __restrict__ lb,
    __half* __restrict__ xc_new, int n) {
  int i = (int)(((size_t)blockIdx.x * blockDim.x + threadIdx.x) >> 6);
  int lane = threadIdx.x & 63;
  if (i >= n) return;
  int e0 = rp_cc[i], e1 = rp_cc[i + 1];
  int cidx = 0; float cw = 0.0f;
  if (e0 + lane < e1) { cidx = srcbuf[e0 + lane]; cw = 1.0f; }
  float self = __half2float(xc_old[(size_t)i * D + lane]);
  float acc = csr_gather_h2(srcbuf, nullptr, xc_old, e0, e1, lane, cidx, cw);
  float h = (1.0f + eps_cc[0]) * self + acc;
  float gin = b_cc[lane];
#pragma unroll
  for (int k = 0; k < 64; ++k)
    gin = fmaf(__shfl(h, k), W_cc[k * 64 + lane], gin);
  float g = fmaxf(gin, 0.0f);
  float m = wave_sum64(g) * (1.0f / 64.0f);
  float d = g - m;
  float var = wave_sum64(d * d) * (1.0f / 64.0f);
  float o = d * rsqrtf(var + LN_EPS) * ls[lane] + lb[lane];
  xc_new[(size_t)i * D + lane] = __float2half(fmaxf(o, 0.0f));
}

// ---------------- output head: wave per row --------------------------------
__global__ __launch_bounds__(256) void out_kernel(
    const __half* __restrict__ xg, const float* __restrict__ W,
    const float* __restrict__ b, float* __restrict__ out, int n) {
  int wid = (int)(((size_t)blockIdx.x * blockDim.x + threadIdx.x) >> 6);
  int lane = threadIdx.x & 63;
  if (wid >= n) return;
  float v = __half2float(xg[(size_t)wid * D + lane]);
  float a0 = wave_sum64(v * W[lane * 3 + 0]) + b[0];
  float a1 = wave_sum64(v * W[lane * 3 + 1]) + b[1];
  float a2 = wave_sum64(v * W[lane * 3 + 2]) + b[2];
  float m = fmaxf(a0, fmaxf(a1, a2));
  float e0 = expf(a0 - m), e1 = expf(a1 - m), e2 = expf(a2 - m);
  float inv = 1.0f / (e0 + e1 + e2);
  if (lane == 0) {
    out[(size_t)wid * 3 + 0] = e0 * inv;
    out[(size_t)wid * 3 + 1] = e1 * inv;
    out[(size_t)wid * 3 + 2] = e2 * inv;
  }
}

extern "C" void kernel_launch(void* const* d_in, const int* in_sizes, int n_in,
                              void* d_out, int out_size, void* d_ws, size_t ws_size,
                              hipStream_t stream) {
  const float* x_glom = (const float*)d_in[0];
  const float* x_cell = (const float*)d_in[1];
  const int*   ei_gg  = (const int*)d_in[2];
  const float* ew_gg  = (const float*)d_in[3];
  const int*   ei_cg  = (const int*)d_in[4];
  const int*   ei_cc  = (const int*)d_in[5];
  const float* W_in_g = (const float*)d_in[6];
  const float* b_in_g = (const float*)d_in[7];
  const float* lnig_s = (const float*)d_in[8];
  const float* lnig_b = (const float*)d_in[9];
  const float* W_in_c = (const float*)d_in[10];
  const float* b_in_c = (const float*)d_in[11];
  const float* lnic_s = (const float*)d_in[12];
  const float* lnic_b = (const float*)d_in[13];
  const float* W_outp = (const float*)d_in[34];
  const float* b_outp = (const float*)d_in[35];

  // ---- workspace layout (~60 MB) ----
  char* W0 = (char*)d_ws;
  __half* xg0 = (__half*)W0;                         W0 += (size_t)NG * D * 2;
  __half* xg1 = (__half*)W0;                         W0 += (size_t)NG * D * 2;
  __half* xc0 = (__half*)W0;                         W0 += (size_t)NC * D * 2;
  __half* xc1 = (__half*)W0;                         W0 += (size_t)NC * D * 2;
  float* dinv = (float*)W0;                          W0 += NG * 4;
  float* nrm  = (float*)W0;                          W0 += EGG * 4;
  int* cnt    = (int*)W0;                            W0 += SCAN_N * 4;
  int* S      = (int*)W0;                            W0 += (SCAN_N + 1) * 4;
  int* bsum   = (int*)W0;                            W0 += SCAN_NBLK * 4;
  int* srcbuf = (int*)W0;                            W0 += (size_t)(EGG + ECG + ECC) * 4;
  // transient region (dead before fc_in writes xc0/xc1): pos arrays + permuted ew
  int* pos_gg = (int*)xc0;
  int* pos_cg = pos_gg + EGG;
  int* pos_cc = pos_cg + ECG;
  float* ewp  = (float*)(pos_cc + ECC);

  dim3 blk(256);
  auto wgrid = [](long long waves) { return dim3((unsigned)((waves + 3) / 4)); };
  auto egrid = [](long long e) { return dim3((unsigned)((e + 255) / 256)); };

  // ---- CSR build: 1 atomic pass + hierarchical scan + atomic-free scatter --
  hipMemsetAsync(cnt, 0, SCAN_N * sizeof(int), stream);
  passA_kernel<<<egrid(ECG), blk, 0, stream>>>(
      ei_gg, ei_cg, ei_cc, cnt, pos_gg, pos_cg, pos_cc);
  scan_blocksum_kernel<<<dim3(SCAN_NBLK), dim3(SCAN_TPB), 0, stream>>>(cnt, bsum);
  scan_bsum_kernel<<<dim3(1), dim3(64), 0, stream>>>(bsum, S);
  scan_final_kernel<<<dim3(SCAN_NBLK), dim3(SCAN_TPB), 0, stream>>>(cnt, bsum, S);
  scatter_kernel<<<egrid(ECG), blk, 0, stream>>>(
      ei_gg, ew_gg, ei_cg, ei_cc, S, pos_gg, pos_cg, pos_cc, srcbuf, ewp);
  deg_kernel<<<wgrid(NG), blk, 0, stream>>>(S, ewp, dinv);
  nrm_kernel<<<wgrid(NG), blk, 0, stream>>>(S, srcbuf, ewp, dinv, nrm);

  // ---- input FCs (xc0 write overwrites the transient pos/ewp region) ----
  fc_in_kernel<<<wgrid(NG), blk, 0, stream>>>(x_glom, W_in_g, b_in_g, lnig_s, lnig_b, xg0, NG);
  fc_in_kernel<<<wgrid(NC), blk, 0, stream>>>(x_cell, W_in_c, b_in_c, lnic_s, lnic_b, xc0, NC);

  // ---- two hetero MP layers (double-buffered) ----
  const int* rp_gg = S;
  const int* rp_cg = S + NG;
  const int* rp_cc = S + 2 * NG;
  __half* xg_cur = xg0; __half* xg_nxt = xg1;
  __half* xc_cur = xc0; __half* xc_nxt = xc1;
  for (int l = 0; l < 2; ++l) {
    const float* const* p = (const float* const*)(d_in + 14 + 10 * l);
    const float* W_gcn = p[0]; const float* b_gcn = p[1];
    const float* eps_cg = p[2]; const float* W_cg = p[3]; const float* b_cg = p[4];
    const float* eps_cc = p[5]; const float* W_cc = p[6]; const float* b_cc = p[7];
    const float* ln_s = p[8]; const float* ln_b = p[9];

    glom_layer_kernel<<<wgrid(NG), blk, 0, stream>>>(
        rp_gg, rp_cg, srcbuf, nrm, xg_cur, xc_cur, dinv,
        W_gcn, b_gcn, eps_cg, W_cg, b_cg, ln_s, ln_b, xg_nxt, NG);
    cell_layer_kernel<<<wgrid(NC), blk, 0, stream>>>(
        rp_cc, srcbuf, xc_cur, eps_cc, W_cc, b_cc, ln_s, ln_b, xc_nxt, NC);

    __half* t;
    t = xg_cur; xg_cur = xg_nxt; xg_nxt = t;
    t = xc_cur; xc_cur = xc_nxt; xc_nxt = t;
  }

  out_kernel<<<wgrid(NG), blk, 0, stream>>>(xg_cur, W_outp, b_outp, (float*)d_out, NG);
}